// Round 22
// baseline (490.467 us; speedup 1.0000x reference)
//
#include <hip/hip_runtime.h>
#include <hip/hip_bf16.h>
#include <math.h>

typedef __hip_bfloat16 bf16;
typedef __attribute__((ext_vector_type(8))) short short8v;
typedef __attribute__((ext_vector_type(4))) float f32x4;

#define BQ 4
#define CCH 192
#define C3 576
#define HWP 16384
#define NHEADS 4
#define CPG 48
#define GH 96

static __device__ __forceinline__ float b2f(bf16 v){ return __bfloat162float(v); }
static __device__ __forceinline__ bf16 f2b(float v){ return __float2bfloat16(v); }
static __device__ __forceinline__ float us2f(unsigned short u){
    union { unsigned u32; float f; } cv; cv.u32 = ((unsigned)u) << 16; return cv.f;
}

// ---------------- x -> xt bf16 transposed [b][p][192] --------------------------------
__global__ __launch_bounds__(256) void xcast_kernel(const float* __restrict__ x,
                                                    bf16* __restrict__ xt)
{
    __shared__ bf16 tile[64][198];
    int t = threadIdx.x;
    int p0 = blockIdx.x * 64;
    int b  = blockIdx.y;
    const float* xb = x + (size_t)b*CCH*HWP;
    #pragma unroll 4
    for (int i = 0; i < 48; ++i) {    // 12288 scalars = 64 px x 192 ch
        int lin = i*256 + t;
        int cc = lin >> 6, pp = lin & 63;
        tile[pp][cc] = f2b(xb[(size_t)cc*HWP + p0 + pp]);
    }
    __syncthreads();
    bf16* dst = xt + ((size_t)b*HWP + p0)*CCH;
    #pragma unroll 4
    for (int i = 0; i < 12; ++i) {    // 3072 ushort4 groups
        int lin = i*256 + t;
        int pp = lin / 48, ch = lin % 48;
        ushort2 u0 = *reinterpret_cast<ushort2*>(&tile[pp][ch*4]);
        ushort2 u1 = *reinterpret_cast<ushort2*>(&tile[pp][ch*4+2]);
        ushort4 v; v.x=u0.x; v.y=u0.y; v.z=u1.x; v.w=u1.y;
        *reinterpret_cast<ushort4*>(dst + (size_t)pp*CCH + ch*4) = v;
    }
}

// ---------------- weights f32 -> bf16 ------------------------------------------------
__global__ void wcvt_kernel(const float* __restrict__ qw, bf16* __restrict__ qwt,
                            const float* __restrict__ pw, bf16* __restrict__ pwt,
                            const float* __restrict__ g1w, bf16* __restrict__ w1t)
{
    int i = blockIdx.x*256 + threadIdx.x;
    if (i < C3*CCH)  qwt[i] = f2b(qw[i]);
    if (i < CCH*CCH) pwt[i] = f2b(pw[i]);
    if (i < GH*CCH)  w1t[i] = f2b(g1w[i]);
}

// ---------------- qkv MFMA GEMM + fused gate (shares A registers) --------------------
__global__ __launch_bounds__(256) void mfma_qkv_gate_kernel(const bf16* __restrict__ xtp,
        const bf16* __restrict__ Wb, bf16* __restrict__ outb,
        const bf16* __restrict__ w1b, const float* __restrict__ b1,
        const float* __restrict__ w2, const float* __restrict__ b2v,
        float* __restrict__ partials)
{
    int t = threadIdx.x;
    int w = t >> 6, l = t & 63;
    int lm = l & 15, lk = l >> 4;
    int p0 = blockIdx.x * 128;
    int b  = blockIdx.y;
    const bf16* xb = xtp + ((size_t)b*HWP + p0 + w*32)*CCH;
    const short8v* a0p = reinterpret_cast<const short8v*>(xb + (size_t)lm*CCH) + lk;
    const short8v* a1p = reinterpret_cast<const short8v*>(xb + (size_t)(16+lm)*CCH) + lk;
    short8v a0[6], a1[6];
    #pragma unroll
    for (int kc = 0; kc < 6; ++kc) { a0[kc] = a0p[kc*4]; a1[kc] = a1p[kc*4]; }
    int pbase = p0 + w*32 + lk*4;
    // ---- phase 1: qkv ----
    for (int ot = 0; ot < 9; ++ot) {
        int o0 = ot*64;
        const short8v* bp[4];
        #pragma unroll
        for (int ni = 0; ni < 4; ++ni)
            bp[ni] = reinterpret_cast<const short8v*>(Wb + (size_t)(o0 + ni*16 + lm)*CCH) + lk;
        f32x4 acc[2][4];
        #pragma unroll
        for (int mi = 0; mi < 2; ++mi)
            #pragma unroll
            for (int ni = 0; ni < 4; ++ni) acc[mi][ni] = (f32x4){0.f,0.f,0.f,0.f};
        #pragma unroll
        for (int kc = 0; kc < 6; ++kc) {
            #pragma unroll
            for (int ni = 0; ni < 4; ++ni) {
                short8v bb = bp[ni][kc*4];
                acc[0][ni] = __builtin_amdgcn_mfma_f32_16x16x32_bf16(a0[kc], bb, acc[0][ni], 0,0,0);
                acc[1][ni] = __builtin_amdgcn_mfma_f32_16x16x32_bf16(a1[kc], bb, acc[1][ni], 0,0,0);
            }
        }
        #pragma unroll
        for (int mi = 0; mi < 2; ++mi)
            #pragma unroll
            for (int ni = 0; ni < 4; ++ni) {
                union { bf16 h[4]; uint2 u; } pk;
                #pragma unroll
                for (int r = 0; r < 4; ++r) pk.h[r] = f2b(acc[mi][ni][r]);
                size_t base = ((size_t)b*C3 + o0 + ni*16 + lm)*HWP + pbase + mi*16;
                *reinterpret_cast<uint2*>(outb + base) = pk.u;
            }
    }
    // ---- phase 2: gate stage1 (reuses a0/a1) ----
    const short8v* gp[6];
    #pragma unroll
    for (int ni = 0; ni < 6; ++ni)
        gp[ni] = reinterpret_cast<const short8v*>(w1b + (size_t)(ni*16 + lm)*CCH) + lk;
    f32x4 gacc[2][6];
    #pragma unroll
    for (int mi = 0; mi < 2; ++mi)
        #pragma unroll
        for (int ni = 0; ni < 6; ++ni) gacc[mi][ni] = (f32x4){0.f,0.f,0.f,0.f};
    #pragma unroll
    for (int kc = 0; kc < 6; ++kc) {
        #pragma unroll
        for (int ni = 0; ni < 6; ++ni) {
            short8v bb = gp[ni][kc*4];
            gacc[0][ni] = __builtin_amdgcn_mfma_f32_16x16x32_bf16(a0[kc], bb, gacc[0][ni], 0,0,0);
            gacc[1][ni] = __builtin_amdgcn_mfma_f32_16x16x32_bf16(a1[kc], bb, gacc[1][ni], 0,0,0);
        }
    }
    float b1v[6], w2v[6];
    #pragma unroll
    for (int ni = 0; ni < 6; ++ni) { b1v[ni] = b1[ni*16+lm]; w2v[ni] = w2[ni*16+lm]; }
    float bias2 = b2v[0];
    float sg_sum = 0.f;
    #pragma unroll
    for (int mi = 0; mi < 2; ++mi)
        #pragma unroll
        for (int r = 0; r < 4; ++r) {
            float part = 0.f;
            #pragma unroll
            for (int ni = 0; ni < 6; ++ni)
                part += w2v[ni] * fmaxf(gacc[mi][ni][r] + b1v[ni], 0.f);
            part += __shfl_xor(part, 1);
            part += __shfl_xor(part, 2);
            part += __shfl_xor(part, 4);
            part += __shfl_xor(part, 8);
            if (lm == 0) sg_sum += 1.f / (1.f + expf(-(part + bias2)));
        }
    __shared__ float red[256];
    red[t] = sg_sum; __syncthreads();
    for (int st = 128; st > 0; st >>= 1) { if (t < st) red[t] += red[t+st]; __syncthreads(); }
    if (t == 0) partials[blockIdx.y*128 + blockIdx.x] = red[0];
}

// ---------------- proj MFMA GEMM: LDS epilogue + add bf16 out_conv -> f32 out --------
__global__ __launch_bounds__(256) void mfma_projf_kernel(const bf16* __restrict__ xtp,
        const bf16* __restrict__ Wb, const bf16* __restrict__ oconv, float* __restrict__ outf)
{
    __shared__ float epf[64][133];
    int t = threadIdx.x;
    int w = t >> 6, l = t & 63;
    int lm = l & 15, lk = l >> 4;
    int p0 = blockIdx.x * 128;
    int o0 = blockIdx.y * 64;
    int b  = blockIdx.z;
    const bf16* xb = xtp + ((size_t)b*HWP + p0 + w*32)*CCH;
    const short8v* a0p = reinterpret_cast<const short8v*>(xb + (size_t)lm*CCH) + lk;
    const short8v* a1p = reinterpret_cast<const short8v*>(xb + (size_t)(16+lm)*CCH) + lk;
    const short8v* bp[4];
    #pragma unroll
    for (int ni = 0; ni < 4; ++ni)
        bp[ni] = reinterpret_cast<const short8v*>(Wb + (size_t)(o0 + ni*16 + lm)*CCH) + lk;
    f32x4 acc[2][4];
    #pragma unroll
    for (int mi = 0; mi < 2; ++mi)
        #pragma unroll
        for (int ni = 0; ni < 4; ++ni) acc[mi][ni] = (f32x4){0.f,0.f,0.f,0.f};
    #pragma unroll
    for (int kc = 0; kc < 6; ++kc) {          // K = 192
        short8v a0 = a0p[kc*4];
        short8v a1 = a1p[kc*4];
        #pragma unroll
        for (int ni = 0; ni < 4; ++ni) {
            short8v bb = bp[ni][kc*4];
            acc[0][ni] = __builtin_amdgcn_mfma_f32_16x16x32_bf16(a0, bb, acc[0][ni], 0,0,0);
            acc[1][ni] = __builtin_amdgcn_mfma_f32_16x16x32_bf16(a1, bb, acc[1][ni], 0,0,0);
        }
    }
    #pragma unroll
    for (int mi = 0; mi < 2; ++mi)
        #pragma unroll
        for (int ni = 0; ni < 4; ++ni)
            #pragma unroll
            for (int r = 0; r < 4; ++r)
                epf[ni*16 + lm][w*32 + mi*16 + lk*4 + r] = acc[mi][ni][r];
    __syncthreads();
    #pragma unroll 4
    for (int i = 0; i < 16; ++i) {
        int lin = i*256 + t;
        int ol = lin >> 6, pc = (lin & 63)*2;
        float v0 = epf[ol][pc], v1 = epf[ol][pc+1];
        size_t base = ((size_t)b*CCH + o0 + ol)*HWP + p0 + pc;
        unsigned u = *reinterpret_cast<const unsigned*>(oconv + base);
        float2 res;
        res.x = v0 + us2f((unsigned short)(u & 0xffffu));
        res.y = v1 + us2f((unsigned short)(u >> 16));
        *reinterpret_cast<float2*>(outf + base) = res;
    }
}

// ---------------- depthwise 3x3, bf16 LDS + vectorized staging -----------------------
__global__ __launch_bounds__(256) void dw3x3_kernel(const bf16* __restrict__ in,
        const float* __restrict__ w, bf16* __restrict__ out)
{
    __shared__ bf16 pl[10][144];      // 2880 B
    int t = threadIdx.x;
    int y0 = blockIdx.x * 8;
    int ch = blockIdx.y;
    int b  = blockIdx.z;
    const bf16* base = in + ((size_t)b*C3 + ch)*HWP;
    if (t < 80) {
        int row = t >> 3, q = t & 7;
        int col = (q < 2) ? (2*q) : (132 + 2*(q-2));
        *reinterpret_cast<unsigned*>(&pl[row][col]) = 0u;
    }
    for (int idx = t; idx < 320; idx += 256) {
        int row = idx >> 5, j = idx & 31;
        int yy = y0 + row - 1;
        ushort4 v = {0,0,0,0};
        if (yy >= 0 && yy < 128)
            v = *reinterpret_cast<const ushort4*>(base + yy*128 + 4*j);
        *reinterpret_cast<ushort4*>(&pl[row][4 + 4*j]) = v;
    }
    __syncthreads();
    const float* wz = w + ch*27 + 9;
    float wk[9];
    #pragma unroll
    for (int k = 0; k < 9; ++k) wk[k] = wz[k];
    int ty = t >> 5;
    int x0 = (t & 31) * 4;
    float acc[4] = {0,0,0,0};
    #pragma unroll
    for (int r = 0; r < 3; ++r) {
        const bf16* row = &pl[ty+r][0];
        unsigned short um = *reinterpret_cast<const unsigned short*>(row + x0 + 3);
        ushort4 u4 = *reinterpret_cast<const ushort4*>(row + x0 + 4);
        unsigned up = *reinterpret_cast<const unsigned*>(row + x0 + 8);
        float vals[6];
        vals[0] = us2f(um);
        vals[1] = us2f(u4.x); vals[2] = us2f(u4.y); vals[3] = us2f(u4.z); vals[4] = us2f(u4.w);
        vals[5] = us2f((unsigned short)(up & 0xffffu));
        #pragma unroll
        for (int px = 0; px < 4; ++px)
            acc[px] += wk[r*3+0]*vals[px] + wk[r*3+1]*vals[px+1] + wk[r*3+2]*vals[px+2];
    }
    bf16 tmp[4];
    #pragma unroll
    for (int px = 0; px < 4; ++px) tmp[px] = f2b(acc[px]);
    bf16* ob = out + ((size_t)b*C3 + ch)*HWP + (size_t)(y0+ty)*128 + x0;
    *reinterpret_cast<uint2*>(ob) = *reinterpret_cast<uint2*>(tmp);
}

// ---------------- fc mixing: 16 px per block (33 KB LDS -> 4 blocks/CU) --------------
__global__ void fc9_kernel(const bf16* __restrict__ qkv, const float* __restrict__ fcw,
                           const float* __restrict__ fcb, bf16* __restrict__ f9s)
{
    __shared__ bf16 raw[16*576];      // 18432 B
    __shared__ bf16 f9t[432*16];      // 13824 B
    __shared__ float fw[9][12];
    __shared__ float fb[9];
    int t = threadIdx.x;
    int blk = blockIdx.x;
    int b = blk >> 10;                // 1024 blocks per batch, 16 px each
    int n0 = (blk & 1023) * 16;
    if (t < 108) fw[t/12][t%12] = fcw[t];
    if (t < 9)   fb[t] = fcb[t];
    const uint4* s4 = reinterpret_cast<const uint4*>(qkv + (size_t)b*C3*HWP + (size_t)n0*576);
    uint4* d4 = reinterpret_cast<uint4*>(raw);
    for (int idx = t; idx < 1152; idx += 256) d4[idx] = s4[idx];
    __syncthreads();
    #pragma unroll
    for (int s = 0; s < 3; ++s) {
        int q = t + s*256;            // 768 (cc,n) pairs
        int cc = q % 48, n = q / 48;
        float acc[9];
        #pragma unroll
        for (int o = 0; o < 9; ++o) acc[o] = fb[o];
        #pragma unroll
        for (int g = 0; g < 12; ++g) {
            float v = b2f(raw[n*576 + g*48 + cc]);
            #pragma unroll
            for (int o = 0; o < 9; ++o) acc[o] += fw[o][g]*v;
        }
        #pragma unroll
        for (int o = 0; o < 9; ++o) f9t[(cc*9+o)*16 + n] = f2b(acc[o]);
    }
    __syncthreads();
    bf16* dst = f9s + (size_t)b*432*HWP + n0;
    for (int idx = t; idx < 432*16; idx += 256) {
        int r = idx >> 4, m = idx & 15;
        dst[(size_t)r*HWP + m] = f9t[idx];
    }
}

// ---------------- grouped 3x3 dep conv -> bf16 out_conv in ws ------------------------
__global__ __launch_bounds__(256) void depconv_kernel(const bf16* __restrict__ f9s,
        const float* __restrict__ depw, const float* __restrict__ depb, bf16* __restrict__ oconv)
{
    __shared__ bf16 pl[9][10][144];   // col = x + 4; 25920 B
    __shared__ float wl[4][84];
    int t = threadIdx.x;
    int y0 = blockIdx.x * 8;
    int gr = blockIdx.y;
    int b  = blockIdx.z;
    const bf16* base = f9s + ((size_t)b*432 + (size_t)gr*9)*HWP;
    for (int idx = t; idx < 4*81; idx += 256) {
        int o = idx / 81, k = idx - o*81;
        int p = k / 9, rk = k - p*9;
        wl[o][k] = depw[(size_t)(gr*4+o)*243 + p*27 + 9 + rk];
    }
    for (int idx = t; idx < 720; idx += 256) {
        int pr = idx >> 3, q = idx & 7;
        int p = pr / 10, row = pr - p*10;
        int col = (q < 2) ? (2*q) : (132 + 2*(q-2));
        *reinterpret_cast<unsigned*>(&pl[p][row][col]) = 0u;
    }
    for (int idx = t; idx < 2880; idx += 256) {
        int p = idx / 320;
        int rem = idx - p*320;
        int row = rem >> 5, j = rem & 31;
        int yy = y0 + row - 1;
        ushort4 v = {0,0,0,0};
        if (yy >= 0 && yy < 128)
            v = *reinterpret_cast<const ushort4*>(base + (size_t)p*HWP + yy*128 + 4*j);
        *reinterpret_cast<ushort4*>(&pl[p][row][4 + 4*j]) = v;
    }
    __syncthreads();
    int ty = t >> 5;
    int x0 = (t & 31) * 4;
    float acc[4][4];
    #pragma unroll
    for (int o = 0; o < 4; ++o) {
        float bv = depb[gr*4+o];
        acc[o][0]=bv; acc[o][1]=bv; acc[o][2]=bv; acc[o][3]=bv;
    }
    #pragma unroll
    for (int p = 0; p < 9; ++p) {
        #pragma unroll
        for (int r = 0; r < 3; ++r) {
            const bf16* row = &pl[p][ty+r][0];
            unsigned short um = *reinterpret_cast<const unsigned short*>(row + x0 + 3);
            ushort4 u4 = *reinterpret_cast<const ushort4*>(row + x0 + 4);
            unsigned up = *reinterpret_cast<const unsigned*>(row + x0 + 8);
            float vals[6];
            vals[0] = us2f(um);
            vals[1] = us2f(u4.x); vals[2] = us2f(u4.y); vals[3] = us2f(u4.z); vals[4] = us2f(u4.w);
            vals[5] = us2f((unsigned short)(up & 0xffffu));
            #pragma unroll
            for (int o = 0; o < 4; ++o) {
                float w0 = wl[o][p*9+r*3+0];
                float w1 = wl[o][p*9+r*3+1];
                float w2 = wl[o][p*9+r*3+2];
                #pragma unroll
                for (int px = 0; px < 4; ++px)
                    acc[o][px] += w0*vals[px] + w1*vals[px+1] + w2*vals[px+2];
            }
        }
    }
    bf16* ob = oconv + ((size_t)b*192 + (size_t)gr*4)*HWP + (size_t)(y0+ty)*128 + x0;
    #pragma unroll
    for (int o = 0; o < 4; ++o) {
        union { bf16 h[4]; uint2 u; } pk;
        #pragma unroll
        for (int px = 0; px < 4; ++px) pk.h[px] = f2b(acc[o][px]);
        *reinterpret_cast<uint2*>(ob + (size_t)o*HWP) = pk.u;
    }
}

// ---------------- QK^T partials via MFMA + fused q/k row sum-of-squares --------------
__global__ __launch_bounds__(256) void attn_dot_kernel(const bf16* __restrict__ qkv,
        float* __restrict__ partial, float* __restrict__ ssqbuf)
{
    __shared__ float ldsred[4][2304];   // 36864 B
    __shared__ float sqq[4][48];
    __shared__ float sqk[4][48];
    int bh = blockIdx.x, ps = blockIdx.y;
    int b = bh >> 2, h = bh & 3;
    int t = threadIdx.x;
    int w = t >> 6, l = t & 63;
    int lm = l & 15, lk = l >> 4;
    int K0 = ps*1024 + w*256;
    const bf16* qbase = qkv + ((size_t)b*C3 + h*48) * HWP + K0;
    const bf16* kbase = qbase + (size_t)192*HWP;
    const short8v* ap[3];
    const short8v* bp[3];
    #pragma unroll
    for (int mi = 0; mi < 3; ++mi)
        ap[mi] = reinterpret_cast<const short8v*>(qbase + (size_t)(mi*16+lm)*HWP) + lk;
    #pragma unroll
    for (int ni = 0; ni < 3; ++ni)
        bp[ni] = reinterpret_cast<const short8v*>(kbase + (size_t)(ni*16+lm)*HWP) + lk;
    f32x4 acc[3][3];
    #pragma unroll
    for (int mi = 0; mi < 3; ++mi)
        #pragma unroll
        for (int ni = 0; ni < 3; ++ni) acc[mi][ni] = (f32x4){0.f,0.f,0.f,0.f};
    float ssqa[3] = {0.f,0.f,0.f};
    float ssqb[3] = {0.f,0.f,0.f};
    #pragma unroll
    for (int kc = 0; kc < 8; ++kc) {    // 256 = 8 x 32
        short8v a[3], bb[3];
        #pragma unroll
        for (int mi = 0; mi < 3; ++mi) a[mi] = ap[mi][kc*4];
        #pragma unroll
        for (int ni = 0; ni < 3; ++ni) bb[ni] = bp[ni][kc*4];
        #pragma unroll
        for (int mi = 0; mi < 3; ++mi)
            #pragma unroll
            for (int ni = 0; ni < 3; ++ni)
                acc[mi][ni] = __builtin_amdgcn_mfma_f32_16x16x32_bf16(a[mi], bb[ni], acc[mi][ni], 0,0,0);
        #pragma unroll
        for (int mi = 0; mi < 3; ++mi)
            #pragma unroll
            for (int j = 0; j < 8; ++j) {
                float va = us2f((unsigned short)a[mi][j]);
                float vb = us2f((unsigned short)bb[mi][j]);
                ssqa[mi] += va*va;
                ssqb[mi] += vb*vb;
            }
    }
    #pragma unroll
    for (int mi = 0; mi < 3; ++mi) {
        float va = ssqa[mi];
        va += __shfl_xor(va, 16); va += __shfl_xor(va, 32);
        float vb = ssqb[mi];
        vb += __shfl_xor(vb, 16); vb += __shfl_xor(vb, 32);
        if (lk == 0) { sqq[w][mi*16+lm] = va; sqk[w][mi*16+lm] = vb; }
    }
    #pragma unroll
    for (int mi = 0; mi < 3; ++mi)
        #pragma unroll
        for (int ni = 0; ni < 3; ++ni)
            #pragma unroll
            for (int r = 0; r < 4; ++r)
                ldsred[w][(mi*16 + lk*4 + r)*48 + ni*16 + lm] = acc[mi][ni][r];
    __syncthreads();
    float* dst = partial + ((size_t)bh*16 + ps)*2304;
    for (int idx = t; idx < 2304; idx += 256)
        dst[idx] = ldsred[0][idx] + ldsred[1][idx] + ldsred[2][idx] + ldsred[3][idx];
    if (t < 96) {
        float s = (t < 48) ? (sqq[0][t] + sqq[1][t] + sqq[2][t] + sqq[3][t])
                           : (sqk[0][t-48] + sqk[1][t-48] + sqk[2][t-48] + sqk[3][t-48]);
        ssqbuf[((size_t)bh*16 + ps)*96 + t] = s;
    }
}

// ---------------- finalize attention: cooperative 256-thread version -----------------
// Phases preserve the exact f32 summation orders of the 64-thread version.
__global__ __launch_bounds__(256) void attn_finalize_kernel(const float* __restrict__ partial,
        const float* __restrict__ ssqbuf, const float* __restrict__ temp,
        const float* __restrict__ gparts, float* __restrict__ A)
{
    __shared__ float amat[48*48];      // summed attention logits (pre-scale)
    __shared__ float qinv[48];
    __shared__ float kinv[48];
    __shared__ float dksh;
    int bh = blockIdx.x; int h = bh & 3;
    int t = threadIdx.x;
    // Phase A: gparts sum (serial order preserved, thread 0)
    if (t == 0) {
        float gs = 0.f;
        for (int k = 0; k < 512; ++k) gs += gparts[k];
        dksh = floorf(48.f * (gs / 65536.f));
    }
    // Phase B: 96 norms, serial ps-order per output
    if (t < 96) {
        float s = 0.f;
        for (int ps = 0; ps < 16; ++ps) s += ssqbuf[((size_t)bh*16 + ps)*96 + t];
        float inv = 1.f / fmaxf(sqrtf(s), 1e-12f);
        if (t < 48) qinv[t] = inv; else kinv[t-48] = inv;
    }
    // Phase C: 2304 partial sums, serial ps-order per output
    const float* pb = partial + (size_t)bh*16*2304;
    for (int idx = t; idx < 2304; idx += 256) {
        float s = 0.f;
        for (int ps = 0; ps < 16; ++ps) s += pb[ps*2304 + idx];
        amat[idx] = s;
    }
    __syncthreads();
    // Phase D: rank/softmax per row (threads 0..47)
    if (t >= 48) return;
    int i = t;
    int dk = (int)dksh;
    if (dk > 48) dk = 48;
    float tm = temp[h];
    float qi = qinv[i];
    float a[48];
    #pragma unroll 8
    for (int j = 0; j < 48; ++j)
        a[j] = amat[i*48 + j] * qi * kinv[j] * tm;
    bool keep[48];
    for (int j = 0; j < 48; ++j) {
        int r = 0;
        float aj = a[j];
        for (int l = 0; l < 48; ++l) {
            float al = a[l];
            r += (al > aj) || (al == aj && l < j);
        }
        keep[j] = (r < dk);
    }
    float m = -1e30f;
    for (int j = 0; j < 48; ++j) if (keep[j]) m = fmaxf(m, a[j]);
    float e[48]; float sum = 0.f;
    for (int j = 0; j < 48; ++j) { e[j] = keep[j] ? expf(a[j]-m) : 0.f; sum += e[j]; }
    float inv = 1.f / sum;
    float* dst = A + (size_t)bh*2304 + i*48;
    for (int j = 0; j < 48; ++j) dst[j] = e[j]*inv;
}

// ---------------- PV: writes out_attn TRANSPOSED [b][p][192]; 4 chunks/block ---------
__global__ void attn_out_kernel(const float* __restrict__ A, const bf16* __restrict__ qkv,
                                bf16* __restrict__ out_attnT)
{
    int bh = blockIdx.x, ps = blockIdx.y;      // ps in 0..63 -> 256-px partition
    int b = bh >> 2, h = bh & 3;
    int t = threadIdx.x;
    __shared__ float As[48*48];
    __shared__ float vs[48][64];
    for (int idx = t; idx < 2304; idx += 256) As[idx] = A[(size_t)bh*2304 + idx];
    const bf16* vbase = qkv + ((size_t)b*C3 + 384 + h*48) * HWP;
    bf16* oT = out_attnT + (size_t)b*HWP*CCH;
    int pp = t & 63, ig = t >> 6;
    for (int chunk = 0; chunk < 4; ++chunk) {
        int pc = ps*256 + chunk*64;
        __syncthreads();
        #pragma unroll
        for (int s = 0; s < 12; ++s) {
            int idx = t + s*256;
            int r = idx >> 6, c = idx & 63;
            vs[r][c] = b2f(vbase[(size_t)r*HWP + pc + c]);
        }
        __syncthreads();
        float acc[12] = {0,0,0,0,0,0,0,0,0,0,0,0};
        for (int j = 0; j < 48; ++j) {
            float vv = vs[j][pp];
            #pragma unroll
            for (int ii = 0; ii < 12; ++ii) acc[ii] += As[(ig*12+ii)*48 + j]*vv;
        }
        bf16* od = oT + (size_t)(pc+pp)*CCH + h*48 + ig*12;
        #pragma unroll
        for (int ii = 0; ii < 12; ++ii)
            od[ii] = f2b(acc[ii]);
    }
}

extern "C" void kernel_launch(void* const* d_in, const int* in_sizes, int n_in,
                              void* d_out, int out_size, void* d_ws, size_t ws_size,
                              hipStream_t stream)
{
    const float* x        = (const float*)d_in[0];
    const float* temp     = (const float*)d_in[1];
    const float* qkv_w    = (const float*)d_in[2];
    const float* qkv_dw_w = (const float*)d_in[3];
    const float* proj_w   = (const float*)d_in[4];
    const float* fc_w     = (const float*)d_in[5];
    const float* fc_b     = (const float*)d_in[6];
    const float* dep_w    = (const float*)d_in[7];
    const float* dep_b    = (const float*)d_in[8];
    const float* gate_w1  = (const float*)d_in[9];
    const float* gate_b1  = (const float*)d_in[10];
    const float* gate_w2  = (const float*)d_in[11];
    const float* gate_b2  = (const float*)d_in[12];
    float* out = (float*)d_out;
    char* ws = (char*)d_ws;

    const size_t SZ_A = (size_t)BQ*C3*HWP*2;           // 75,497,472 B
    bf16* bufA   = (bf16*)(ws);                        // qkv (MFMA out), then f9s
    bf16* qkv_dw = (bf16*)(ws + SZ_A);
    bf16* slotC  = (bf16*)(ws + 2*SZ_A);               // xt, then out_attnT (25.2 MB)
    char* tail   = ws + 2*SZ_A + (size_t)BQ*HWP*CCH*2;
    float* attn_partial = (float*)tail;                // 16*16*2304 f32
    float* Abuf    = attn_partial + 16*16*2304;
    float* qkssq   = Abuf + 16*2304;                   // 16*16*96 f32
    float* gparts  = qkssq + 16*16*96;                 // 512 f32
    bf16*  qwt     = (bf16*)(gparts + 512);            // 576*192 bf16
    bf16*  pwt     = qwt + C3*CCH;                     // 192*192 bf16
    bf16*  w1t     = pwt + CCH*CCH;                    // 96*192 bf16
    bf16*  oconv   = w1t + GH*CCH;                     // BQ*192*HWP bf16 (25.2 MB)

    // 0. weight convert
    wcvt_kernel<<<dim3(432), 256, 0, stream>>>(qkv_w, qwt, proj_w, pwt, gate_w1, w1t);
    // 1. x -> xt bf16 [b][p][192]
    xcast_kernel<<<dim3(HWP/64, BQ), 256, 0, stream>>>(x, slotC);
    // 2. qkv + gate fused via MFMA (shared A registers) -> bufA + 512 gate partials
    mfma_qkv_gate_kernel<<<dim3(HWP/128, BQ), 256, 0, stream>>>(
        slotC, qwt, bufA, w1t, gate_b1, gate_w2, gate_b2, gparts);
    // 3. depthwise 3x3 (vectorized bf16 staging)
    dw3x3_kernel<<<dim3(16, C3, BQ), 256, 0, stream>>>(bufA, qkv_dw_w, qkv_dw);
    // 4. fc mixing (16 px/block, reuses bufA as f9s)
    fc9_kernel<<<dim3((BQ*HWP)/16), 256, 0, stream>>>(qkv_dw, fc_w, fc_b, bufA);
    // 5. grouped dep conv -> bf16 out_conv in ws
    depconv_kernel<<<dim3(16, 48, BQ), 256, 0, stream>>>(bufA, dep_w, dep_b, oconv);
    // 6. QK^T partials via MFMA + fused q/k sum-of-squares
    attn_dot_kernel<<<dim3(16,16), 256, 0, stream>>>(qkv_dw, attn_partial, qkssq);
    // 7. finalize (cooperative 256-thread): norms, dynamic-k mask, softmax
    attn_finalize_kernel<<<dim3(16), 256, 0, stream>>>(attn_partial, qkssq, temp, gparts, Abuf);
    // 8. PV -> out_attnT [b][p][192], 64 pixel-partitions (4 blocks/CU)
    attn_out_kernel<<<dim3(16,64), 256, 0, stream>>>(Abuf, qkv_dw, slotC);
    // 9. proj via MFMA + add bf16 out_conv -> single f32 store to d_out
    mfma_projf_kernel<<<dim3(HWP/128, CCH/64, BQ), 256, 0, stream>>>(slotC, pwt, oconv, out);
}

// Round 23
// 485.560 us; speedup vs baseline: 1.0101x; 1.0101x over previous
//
#include <hip/hip_runtime.h>
#include <hip/hip_bf16.h>
#include <math.h>

typedef __hip_bfloat16 bf16;
typedef __attribute__((ext_vector_type(8))) short short8v;
typedef __attribute__((ext_vector_type(4))) float f32x4;

#define BQ 4
#define CCH 192
#define C3 576
#define HWP 16384
#define NHEADS 4
#define CPG 48
#define GH 96

static __device__ __forceinline__ float b2f(bf16 v){ return __bfloat162float(v); }
static __device__ __forceinline__ bf16 f2b(float v){ return __float2bfloat16(v); }
static __device__ __forceinline__ float us2f(unsigned short u){
    union { unsigned u32; float f; } cv; cv.u32 = ((unsigned)u) << 16; return cv.f;
}

// ---------------- x -> xt bf16 transposed [b][p][192] --------------------------------
__global__ __launch_bounds__(256) void xcast_kernel(const float* __restrict__ x,
                                                    bf16* __restrict__ xt)
{
    __shared__ bf16 tile[64][198];
    int t = threadIdx.x;
    int p0 = blockIdx.x * 64;
    int b  = blockIdx.y;
    const float* xb = x + (size_t)b*CCH*HWP;
    #pragma unroll 4
    for (int i = 0; i < 48; ++i) {    // 12288 scalars = 64 px x 192 ch
        int lin = i*256 + t;
        int cc = lin >> 6, pp = lin & 63;
        tile[pp][cc] = f2b(xb[(size_t)cc*HWP + p0 + pp]);
    }
    __syncthreads();
    bf16* dst = xt + ((size_t)b*HWP + p0)*CCH;
    #pragma unroll 4
    for (int i = 0; i < 12; ++i) {    // 3072 ushort4 groups
        int lin = i*256 + t;
        int pp = lin / 48, ch = lin % 48;
        ushort2 u0 = *reinterpret_cast<ushort2*>(&tile[pp][ch*4]);
        ushort2 u1 = *reinterpret_cast<ushort2*>(&tile[pp][ch*4+2]);
        ushort4 v; v.x=u0.x; v.y=u0.y; v.z=u1.x; v.w=u1.y;
        *reinterpret_cast<ushort4*>(dst + (size_t)pp*CCH + ch*4) = v;
    }
}

// ---------------- weights f32 -> bf16 ------------------------------------------------
__global__ void wcvt_kernel(const float* __restrict__ qw, bf16* __restrict__ qwt,
                            const float* __restrict__ pw, bf16* __restrict__ pwt,
                            const float* __restrict__ g1w, bf16* __restrict__ w1t)
{
    int i = blockIdx.x*256 + threadIdx.x;
    if (i < C3*CCH)  qwt[i] = f2b(qw[i]);
    if (i < CCH*CCH) pwt[i] = f2b(pw[i]);
    if (i < GH*CCH)  w1t[i] = f2b(g1w[i]);
}

// ---------------- qkv MFMA GEMM + fused gate (shares A registers) --------------------
__global__ __launch_bounds__(256) void mfma_qkv_gate_kernel(const bf16* __restrict__ xtp,
        const bf16* __restrict__ Wb, bf16* __restrict__ outb,
        const bf16* __restrict__ w1b, const float* __restrict__ b1,
        const float* __restrict__ w2, const float* __restrict__ b2v,
        float* __restrict__ partials)
{
    int t = threadIdx.x;
    int w = t >> 6, l = t & 63;
    int lm = l & 15, lk = l >> 4;
    int p0 = blockIdx.x * 128;
    int b  = blockIdx.y;
    const bf16* xb = xtp + ((size_t)b*HWP + p0 + w*32)*CCH;
    const short8v* a0p = reinterpret_cast<const short8v*>(xb + (size_t)lm*CCH) + lk;
    const short8v* a1p = reinterpret_cast<const short8v*>(xb + (size_t)(16+lm)*CCH) + lk;
    short8v a0[6], a1[6];
    #pragma unroll
    for (int kc = 0; kc < 6; ++kc) { a0[kc] = a0p[kc*4]; a1[kc] = a1p[kc*4]; }
    int pbase = p0 + w*32 + lk*4;
    // ---- phase 1: qkv ----
    for (int ot = 0; ot < 9; ++ot) {
        int o0 = ot*64;
        const short8v* bp[4];
        #pragma unroll
        for (int ni = 0; ni < 4; ++ni)
            bp[ni] = reinterpret_cast<const short8v*>(Wb + (size_t)(o0 + ni*16 + lm)*CCH) + lk;
        f32x4 acc[2][4];
        #pragma unroll
        for (int mi = 0; mi < 2; ++mi)
            #pragma unroll
            for (int ni = 0; ni < 4; ++ni) acc[mi][ni] = (f32x4){0.f,0.f,0.f,0.f};
        #pragma unroll
        for (int kc = 0; kc < 6; ++kc) {
            #pragma unroll
            for (int ni = 0; ni < 4; ++ni) {
                short8v bb = bp[ni][kc*4];
                acc[0][ni] = __builtin_amdgcn_mfma_f32_16x16x32_bf16(a0[kc], bb, acc[0][ni], 0,0,0);
                acc[1][ni] = __builtin_amdgcn_mfma_f32_16x16x32_bf16(a1[kc], bb, acc[1][ni], 0,0,0);
            }
        }
        #pragma unroll
        for (int mi = 0; mi < 2; ++mi)
            #pragma unroll
            for (int ni = 0; ni < 4; ++ni) {
                union { bf16 h[4]; uint2 u; } pk;
                #pragma unroll
                for (int r = 0; r < 4; ++r) pk.h[r] = f2b(acc[mi][ni][r]);
                size_t base = ((size_t)b*C3 + o0 + ni*16 + lm)*HWP + pbase + mi*16;
                *reinterpret_cast<uint2*>(outb + base) = pk.u;
            }
    }
    // ---- phase 2: gate stage1 (reuses a0/a1) ----
    const short8v* gp[6];
    #pragma unroll
    for (int ni = 0; ni < 6; ++ni)
        gp[ni] = reinterpret_cast<const short8v*>(w1b + (size_t)(ni*16 + lm)*CCH) + lk;
    f32x4 gacc[2][6];
    #pragma unroll
    for (int mi = 0; mi < 2; ++mi)
        #pragma unroll
        for (int ni = 0; ni < 6; ++ni) gacc[mi][ni] = (f32x4){0.f,0.f,0.f,0.f};
    #pragma unroll
    for (int kc = 0; kc < 6; ++kc) {
        #pragma unroll
        for (int ni = 0; ni < 6; ++ni) {
            short8v bb = gp[ni][kc*4];
            gacc[0][ni] = __builtin_amdgcn_mfma_f32_16x16x32_bf16(a0[kc], bb, gacc[0][ni], 0,0,0);
            gacc[1][ni] = __builtin_amdgcn_mfma_f32_16x16x32_bf16(a1[kc], bb, gacc[1][ni], 0,0,0);
        }
    }
    float b1v[6], w2v[6];
    #pragma unroll
    for (int ni = 0; ni < 6; ++ni) { b1v[ni] = b1[ni*16+lm]; w2v[ni] = w2[ni*16+lm]; }
    float bias2 = b2v[0];
    float sg_sum = 0.f;
    #pragma unroll
    for (int mi = 0; mi < 2; ++mi)
        #pragma unroll
        for (int r = 0; r < 4; ++r) {
            float part = 0.f;
            #pragma unroll
            for (int ni = 0; ni < 6; ++ni)
                part += w2v[ni] * fmaxf(gacc[mi][ni][r] + b1v[ni], 0.f);
            part += __shfl_xor(part, 1);
            part += __shfl_xor(part, 2);
            part += __shfl_xor(part, 4);
            part += __shfl_xor(part, 8);
            if (lm == 0) sg_sum += 1.f / (1.f + expf(-(part + bias2)));
        }
    __shared__ float red[256];
    red[t] = sg_sum; __syncthreads();
    for (int st = 128; st > 0; st >>= 1) { if (t < st) red[t] += red[t+st]; __syncthreads(); }
    if (t == 0) partials[blockIdx.y*128 + blockIdx.x] = red[0];
}

// ---------------- proj MFMA GEMM: LDS epilogue + add bf16 out_conv -> f32 out --------
__global__ __launch_bounds__(256) void mfma_projf_kernel(const bf16* __restrict__ xtp,
        const bf16* __restrict__ Wb, const bf16* __restrict__ oconv, float* __restrict__ outf)
{
    __shared__ float epf[64][133];
    int t = threadIdx.x;
    int w = t >> 6, l = t & 63;
    int lm = l & 15, lk = l >> 4;
    int p0 = blockIdx.x * 128;
    int o0 = blockIdx.y * 64;
    int b  = blockIdx.z;
    const bf16* xb = xtp + ((size_t)b*HWP + p0 + w*32)*CCH;
    const short8v* a0p = reinterpret_cast<const short8v*>(xb + (size_t)lm*CCH) + lk;
    const short8v* a1p = reinterpret_cast<const short8v*>(xb + (size_t)(16+lm)*CCH) + lk;
    const short8v* bp[4];
    #pragma unroll
    for (int ni = 0; ni < 4; ++ni)
        bp[ni] = reinterpret_cast<const short8v*>(Wb + (size_t)(o0 + ni*16 + lm)*CCH) + lk;
    f32x4 acc[2][4];
    #pragma unroll
    for (int mi = 0; mi < 2; ++mi)
        #pragma unroll
        for (int ni = 0; ni < 4; ++ni) acc[mi][ni] = (f32x4){0.f,0.f,0.f,0.f};
    #pragma unroll
    for (int kc = 0; kc < 6; ++kc) {          // K = 192
        short8v a0 = a0p[kc*4];
        short8v a1 = a1p[kc*4];
        #pragma unroll
        for (int ni = 0; ni < 4; ++ni) {
            short8v bb = bp[ni][kc*4];
            acc[0][ni] = __builtin_amdgcn_mfma_f32_16x16x32_bf16(a0, bb, acc[0][ni], 0,0,0);
            acc[1][ni] = __builtin_amdgcn_mfma_f32_16x16x32_bf16(a1, bb, acc[1][ni], 0,0,0);
        }
    }
    #pragma unroll
    for (int mi = 0; mi < 2; ++mi)
        #pragma unroll
        for (int ni = 0; ni < 4; ++ni)
            #pragma unroll
            for (int r = 0; r < 4; ++r)
                epf[ni*16 + lm][w*32 + mi*16 + lk*4 + r] = acc[mi][ni][r];
    __syncthreads();
    #pragma unroll 4
    for (int i = 0; i < 16; ++i) {
        int lin = i*256 + t;
        int ol = lin >> 6, pc = (lin & 63)*2;
        float v0 = epf[ol][pc], v1 = epf[ol][pc+1];
        size_t base = ((size_t)b*CCH + o0 + ol)*HWP + p0 + pc;
        unsigned u = *reinterpret_cast<const unsigned*>(oconv + base);
        float2 res;
        res.x = v0 + us2f((unsigned short)(u & 0xffffu));
        res.y = v1 + us2f((unsigned short)(u >> 16));
        *reinterpret_cast<float2*>(outf + base) = res;
    }
}

// ---------------- depthwise 3x3, bf16 LDS + vectorized staging -----------------------
__global__ __launch_bounds__(256) void dw3x3_kernel(const bf16* __restrict__ in,
        const float* __restrict__ w, bf16* __restrict__ out)
{
    __shared__ bf16 pl[10][144];      // 2880 B
    int t = threadIdx.x;
    int y0 = blockIdx.x * 8;
    int ch = blockIdx.y;
    int b  = blockIdx.z;
    const bf16* base = in + ((size_t)b*C3 + ch)*HWP;
    if (t < 80) {
        int row = t >> 3, q = t & 7;
        int col = (q < 2) ? (2*q) : (132 + 2*(q-2));
        *reinterpret_cast<unsigned*>(&pl[row][col]) = 0u;
    }
    for (int idx = t; idx < 320; idx += 256) {
        int row = idx >> 5, j = idx & 31;
        int yy = y0 + row - 1;
        ushort4 v = {0,0,0,0};
        if (yy >= 0 && yy < 128)
            v = *reinterpret_cast<const ushort4*>(base + yy*128 + 4*j);
        *reinterpret_cast<ushort4*>(&pl[row][4 + 4*j]) = v;
    }
    __syncthreads();
    const float* wz = w + ch*27 + 9;
    float wk[9];
    #pragma unroll
    for (int k = 0; k < 9; ++k) wk[k] = wz[k];
    int ty = t >> 5;
    int x0 = (t & 31) * 4;
    float acc[4] = {0,0,0,0};
    #pragma unroll
    for (int r = 0; r < 3; ++r) {
        const bf16* row = &pl[ty+r][0];
        unsigned short um = *reinterpret_cast<const unsigned short*>(row + x0 + 3);
        ushort4 u4 = *reinterpret_cast<const ushort4*>(row + x0 + 4);
        unsigned up = *reinterpret_cast<const unsigned*>(row + x0 + 8);
        float vals[6];
        vals[0] = us2f(um);
        vals[1] = us2f(u4.x); vals[2] = us2f(u4.y); vals[3] = us2f(u4.z); vals[4] = us2f(u4.w);
        vals[5] = us2f((unsigned short)(up & 0xffffu));
        #pragma unroll
        for (int px = 0; px < 4; ++px)
            acc[px] += wk[r*3+0]*vals[px] + wk[r*3+1]*vals[px+1] + wk[r*3+2]*vals[px+2];
    }
    bf16 tmp[4];
    #pragma unroll
    for (int px = 0; px < 4; ++px) tmp[px] = f2b(acc[px]);
    bf16* ob = out + ((size_t)b*C3 + ch)*HWP + (size_t)(y0+ty)*128 + x0;
    *reinterpret_cast<uint2*>(ob) = *reinterpret_cast<uint2*>(tmp);
}

// ---------------- fc mixing: 16 px per block (33 KB LDS -> 4 blocks/CU) --------------
__global__ void fc9_kernel(const bf16* __restrict__ qkv, const float* __restrict__ fcw,
                           const float* __restrict__ fcb, bf16* __restrict__ f9s)
{
    __shared__ bf16 raw[16*576];      // 18432 B
    __shared__ bf16 f9t[432*16];      // 13824 B
    __shared__ float fw[9][12];
    __shared__ float fb[9];
    int t = threadIdx.x;
    int blk = blockIdx.x;
    int b = blk >> 10;                // 1024 blocks per batch, 16 px each
    int n0 = (blk & 1023) * 16;
    if (t < 108) fw[t/12][t%12] = fcw[t];
    if (t < 9)   fb[t] = fcb[t];
    const uint4* s4 = reinterpret_cast<const uint4*>(qkv + (size_t)b*C3*HWP + (size_t)n0*576);
    uint4* d4 = reinterpret_cast<uint4*>(raw);
    for (int idx = t; idx < 1152; idx += 256) d4[idx] = s4[idx];
    __syncthreads();
    #pragma unroll
    for (int s = 0; s < 3; ++s) {
        int q = t + s*256;            // 768 (cc,n) pairs
        int cc = q % 48, n = q / 48;
        float acc[9];
        #pragma unroll
        for (int o = 0; o < 9; ++o) acc[o] = fb[o];
        #pragma unroll
        for (int g = 0; g < 12; ++g) {
            float v = b2f(raw[n*576 + g*48 + cc]);
            #pragma unroll
            for (int o = 0; o < 9; ++o) acc[o] += fw[o][g]*v;
        }
        #pragma unroll
        for (int o = 0; o < 9; ++o) f9t[(cc*9+o)*16 + n] = f2b(acc[o]);
    }
    __syncthreads();
    bf16* dst = f9s + (size_t)b*432*HWP + n0;
    for (int idx = t; idx < 432*16; idx += 256) {
        int r = idx >> 4, m = idx & 15;
        dst[(size_t)r*HWP + m] = f9t[idx];
    }
}

// ---------------- grouped 3x3 dep conv -> bf16 out_conv in ws ------------------------
__global__ __launch_bounds__(256) void depconv_kernel(const bf16* __restrict__ f9s,
        const float* __restrict__ depw, const float* __restrict__ depb, bf16* __restrict__ oconv)
{
    __shared__ bf16 pl[9][10][144];   // col = x + 4; 25920 B
    __shared__ float wl[4][84];
    int t = threadIdx.x;
    int y0 = blockIdx.x * 8;
    int gr = blockIdx.y;
    int b  = blockIdx.z;
    const bf16* base = f9s + ((size_t)b*432 + (size_t)gr*9)*HWP;
    for (int idx = t; idx < 4*81; idx += 256) {
        int o = idx / 81, k = idx - o*81;
        int p = k / 9, rk = k - p*9;
        wl[o][k] = depw[(size_t)(gr*4+o)*243 + p*27 + 9 + rk];
    }
    for (int idx = t; idx < 720; idx += 256) {
        int pr = idx >> 3, q = idx & 7;
        int p = pr / 10, row = pr - p*10;
        int col = (q < 2) ? (2*q) : (132 + 2*(q-2));
        *reinterpret_cast<unsigned*>(&pl[p][row][col]) = 0u;
    }
    for (int idx = t; idx < 2880; idx += 256) {
        int p = idx / 320;
        int rem = idx - p*320;
        int row = rem >> 5, j = rem & 31;
        int yy = y0 + row - 1;
        ushort4 v = {0,0,0,0};
        if (yy >= 0 && yy < 128)
            v = *reinterpret_cast<const ushort4*>(base + (size_t)p*HWP + yy*128 + 4*j);
        *reinterpret_cast<ushort4*>(&pl[p][row][4 + 4*j]) = v;
    }
    __syncthreads();
    int ty = t >> 5;
    int x0 = (t & 31) * 4;
    float acc[4][4];
    #pragma unroll
    for (int o = 0; o < 4; ++o) {
        float bv = depb[gr*4+o];
        acc[o][0]=bv; acc[o][1]=bv; acc[o][2]=bv; acc[o][3]=bv;
    }
    #pragma unroll
    for (int p = 0; p < 9; ++p) {
        #pragma unroll
        for (int r = 0; r < 3; ++r) {
            const bf16* row = &pl[p][ty+r][0];
            unsigned short um = *reinterpret_cast<const unsigned short*>(row + x0 + 3);
            ushort4 u4 = *reinterpret_cast<const ushort4*>(row + x0 + 4);
            unsigned up = *reinterpret_cast<const unsigned*>(row + x0 + 8);
            float vals[6];
            vals[0] = us2f(um);
            vals[1] = us2f(u4.x); vals[2] = us2f(u4.y); vals[3] = us2f(u4.z); vals[4] = us2f(u4.w);
            vals[5] = us2f((unsigned short)(up & 0xffffu));
            #pragma unroll
            for (int o = 0; o < 4; ++o) {
                float w0 = wl[o][p*9+r*3+0];
                float w1 = wl[o][p*9+r*3+1];
                float w2 = wl[o][p*9+r*3+2];
                #pragma unroll
                for (int px = 0; px < 4; ++px)
                    acc[o][px] += w0*vals[px] + w1*vals[px+1] + w2*vals[px+2];
            }
        }
    }
    bf16* ob = oconv + ((size_t)b*192 + (size_t)gr*4)*HWP + (size_t)(y0+ty)*128 + x0;
    #pragma unroll
    for (int o = 0; o < 4; ++o) {
        union { bf16 h[4]; uint2 u; } pk;
        #pragma unroll
        for (int px = 0; px < 4; ++px) pk.h[px] = f2b(acc[o][px]);
        *reinterpret_cast<uint2*>(ob + (size_t)o*HWP) = pk.u;
    }
}

// ---------------- QK^T partials via MFMA + fused q/k row sum-of-squares --------------
__global__ __launch_bounds__(256) void attn_dot_kernel(const bf16* __restrict__ qkv,
        float* __restrict__ partial, float* __restrict__ ssqbuf)
{
    __shared__ float ldsred[4][2304];   // 36864 B
    __shared__ float sqq[4][48];
    __shared__ float sqk[4][48];
    int bh = blockIdx.x, ps = blockIdx.y;
    int b = bh >> 2, h = bh & 3;
    int t = threadIdx.x;
    int w = t >> 6, l = t & 63;
    int lm = l & 15, lk = l >> 4;
    int K0 = ps*1024 + w*256;
    const bf16* qbase = qkv + ((size_t)b*C3 + h*48) * HWP + K0;
    const bf16* kbase = qbase + (size_t)192*HWP;
    const short8v* ap[3];
    const short8v* bp[3];
    #pragma unroll
    for (int mi = 0; mi < 3; ++mi)
        ap[mi] = reinterpret_cast<const short8v*>(qbase + (size_t)(mi*16+lm)*HWP) + lk;
    #pragma unroll
    for (int ni = 0; ni < 3; ++ni)
        bp[ni] = reinterpret_cast<const short8v*>(kbase + (size_t)(ni*16+lm)*HWP) + lk;
    f32x4 acc[3][3];
    #pragma unroll
    for (int mi = 0; mi < 3; ++mi)
        #pragma unroll
        for (int ni = 0; ni < 3; ++ni) acc[mi][ni] = (f32x4){0.f,0.f,0.f,0.f};
    float ssqa[3] = {0.f,0.f,0.f};
    float ssqb[3] = {0.f,0.f,0.f};
    #pragma unroll
    for (int kc = 0; kc < 8; ++kc) {    // 256 = 8 x 32
        short8v a[3], bb[3];
        #pragma unroll
        for (int mi = 0; mi < 3; ++mi) a[mi] = ap[mi][kc*4];
        #pragma unroll
        for (int ni = 0; ni < 3; ++ni) bb[ni] = bp[ni][kc*4];
        #pragma unroll
        for (int mi = 0; mi < 3; ++mi)
            #pragma unroll
            for (int ni = 0; ni < 3; ++ni)
                acc[mi][ni] = __builtin_amdgcn_mfma_f32_16x16x32_bf16(a[mi], bb[ni], acc[mi][ni], 0,0,0);
        #pragma unroll
        for (int mi = 0; mi < 3; ++mi)
            #pragma unroll
            for (int j = 0; j < 8; ++j) {
                float va = us2f((unsigned short)a[mi][j]);
                float vb = us2f((unsigned short)bb[mi][j]);
                ssqa[mi] += va*va;
                ssqb[mi] += vb*vb;
            }
    }
    #pragma unroll
    for (int mi = 0; mi < 3; ++mi) {
        float va = ssqa[mi];
        va += __shfl_xor(va, 16); va += __shfl_xor(va, 32);
        float vb = ssqb[mi];
        vb += __shfl_xor(vb, 16); vb += __shfl_xor(vb, 32);
        if (lk == 0) { sqq[w][mi*16+lm] = va; sqk[w][mi*16+lm] = vb; }
    }
    #pragma unroll
    for (int mi = 0; mi < 3; ++mi)
        #pragma unroll
        for (int ni = 0; ni < 3; ++ni)
            #pragma unroll
            for (int r = 0; r < 4; ++r)
                ldsred[w][(mi*16 + lk*4 + r)*48 + ni*16 + lm] = acc[mi][ni][r];
    __syncthreads();
    float* dst = partial + ((size_t)bh*16 + ps)*2304;
    for (int idx = t; idx < 2304; idx += 256)
        dst[idx] = ldsred[0][idx] + ldsred[1][idx] + ldsred[2][idx] + ldsred[3][idx];
    if (t < 96) {
        float s = (t < 48) ? (sqq[0][t] + sqq[1][t] + sqq[2][t] + sqq[3][t])
                           : (sqk[0][t-48] + sqk[1][t-48] + sqk[2][t-48] + sqk[3][t-48]);
        ssqbuf[((size_t)bh*16 + ps)*96 + t] = s;
    }
}

// ---------------- attn partial reduction: 1 amat entry per thread --------------------
// Serial ps-order per entry preserved (bit-identical to previous versions).
__global__ __launch_bounds__(256) void attn_reduce_kernel(const float* __restrict__ partial,
                                                          float* __restrict__ amat)
{
    int bh = blockIdx.x;
    int idx = blockIdx.y*256 + threadIdx.x;   // 9*256 = 2304
    const float* pb = partial + (size_t)bh*16*2304 + idx;
    float s = 0.f;
    #pragma unroll
    for (int ps = 0; ps < 16; ++ps) s += pb[ps*2304];
    amat[(size_t)bh*2304 + idx] = s;
}

// ---------------- finalize attention: norms, dynamic-k mask, softmax -----------------
__global__ __launch_bounds__(256) void attn_finalize_kernel(const float* __restrict__ amat,
        const float* __restrict__ ssqbuf, const float* __restrict__ temp,
        const float* __restrict__ gparts, float* __restrict__ A)
{
    __shared__ float qinv[48];
    __shared__ float kinv[48];
    __shared__ float dksh;
    int bh = blockIdx.x; int h = bh & 3;
    int t = threadIdx.x;
    if (t == 0) {
        float gs = 0.f;
        for (int k = 0; k < 512; ++k) gs += gparts[k];
        dksh = floorf(48.f * (gs / 65536.f));
    }
    if (t < 96) {
        float s = 0.f;
        for (int ps = 0; ps < 16; ++ps) s += ssqbuf[((size_t)bh*16 + ps)*96 + t];
        float inv = 1.f / fmaxf(sqrtf(s), 1e-12f);
        if (t < 48) qinv[t] = inv; else kinv[t-48] = inv;
    }
    __syncthreads();
    if (t >= 48) return;
    int i = t;
    int dk = (int)dksh;
    if (dk > 48) dk = 48;
    float tm = temp[h];
    float qi = qinv[i];
    const float* arow = amat + (size_t)bh*2304 + i*48;
    float a[48];
    #pragma unroll 8
    for (int j = 0; j < 48; ++j)
        a[j] = arow[j] * qi * kinv[j] * tm;
    bool keep[48];
    for (int j = 0; j < 48; ++j) {
        int r = 0;
        float aj = a[j];
        for (int l = 0; l < 48; ++l) {
            float al = a[l];
            r += (al > aj) || (al == aj && l < j);
        }
        keep[j] = (r < dk);
    }
    float m = -1e30f;
    for (int j = 0; j < 48; ++j) if (keep[j]) m = fmaxf(m, a[j]);
    float e[48]; float sum = 0.f;
    for (int j = 0; j < 48; ++j) { e[j] = keep[j] ? expf(a[j]-m) : 0.f; sum += e[j]; }
    float inv = 1.f / sum;
    float* dst = A + (size_t)bh*2304 + i*48;
    for (int j = 0; j < 48; ++j) dst[j] = e[j]*inv;
}

// ---------------- PV: writes out_attn TRANSPOSED [b][p][192]; 4 chunks/block ---------
__global__ void attn_out_kernel(const float* __restrict__ A, const bf16* __restrict__ qkv,
                                bf16* __restrict__ out_attnT)
{
    int bh = blockIdx.x, ps = blockIdx.y;      // ps in 0..63 -> 256-px partition
    int b = bh >> 2, h = bh & 3;
    int t = threadIdx.x;
    __shared__ float As[48*48];
    __shared__ float vs[48][64];
    for (int idx = t; idx < 2304; idx += 256) As[idx] = A[(size_t)bh*2304 + idx];
    const bf16* vbase = qkv + ((size_t)b*C3 + 384 + h*48) * HWP;
    bf16* oT = out_attnT + (size_t)b*HWP*CCH;
    int pp = t & 63, ig = t >> 6;
    for (int chunk = 0; chunk < 4; ++chunk) {
        int pc = ps*256 + chunk*64;
        __syncthreads();
        #pragma unroll
        for (int s = 0; s < 12; ++s) {
            int idx = t + s*256;
            int r = idx >> 6, c = idx & 63;
            vs[r][c] = b2f(vbase[(size_t)r*HWP + pc + c]);
        }
        __syncthreads();
        float acc[12] = {0,0,0,0,0,0,0,0,0,0,0,0};
        for (int j = 0; j < 48; ++j) {
            float vv = vs[j][pp];
            #pragma unroll
            for (int ii = 0; ii < 12; ++ii) acc[ii] += As[(ig*12+ii)*48 + j]*vv;
        }
        bf16* od = oT + (size_t)(pc+pp)*CCH + h*48 + ig*12;
        #pragma unroll
        for (int ii = 0; ii < 12; ++ii)
            od[ii] = f2b(acc[ii]);
    }
}

extern "C" void kernel_launch(void* const* d_in, const int* in_sizes, int n_in,
                              void* d_out, int out_size, void* d_ws, size_t ws_size,
                              hipStream_t stream)
{
    const float* x        = (const float*)d_in[0];
    const float* temp     = (const float*)d_in[1];
    const float* qkv_w    = (const float*)d_in[2];
    const float* qkv_dw_w = (const float*)d_in[3];
    const float* proj_w   = (const float*)d_in[4];
    const float* fc_w     = (const float*)d_in[5];
    const float* fc_b     = (const float*)d_in[6];
    const float* dep_w    = (const float*)d_in[7];
    const float* dep_b    = (const float*)d_in[8];
    const float* gate_w1  = (const float*)d_in[9];
    const float* gate_b1  = (const float*)d_in[10];
    const float* gate_w2  = (const float*)d_in[11];
    const float* gate_b2  = (const float*)d_in[12];
    float* out = (float*)d_out;
    char* ws = (char*)d_ws;

    const size_t SZ_A = (size_t)BQ*C3*HWP*2;           // 75,497,472 B
    bf16* bufA   = (bf16*)(ws);                        // qkv (MFMA out), then f9s
    bf16* qkv_dw = (bf16*)(ws + SZ_A);
    bf16* slotC  = (bf16*)(ws + 2*SZ_A);               // xt, then out_attnT (25.2 MB)
    char* tail   = ws + 2*SZ_A + (size_t)BQ*HWP*CCH*2;
    float* attn_partial = (float*)tail;                // 16*16*2304 f32
    float* Abuf    = attn_partial + 16*16*2304;        // 16*2304
    float* amatbuf = Abuf + 16*2304;                   // 16*2304
    float* qkssq   = amatbuf + 16*2304;                // 16*16*96 f32
    float* gparts  = qkssq + 16*16*96;                 // 512 f32
    bf16*  qwt     = (bf16*)(gparts + 512);            // 576*192 bf16
    bf16*  pwt     = qwt + C3*CCH;                     // 192*192 bf16
    bf16*  w1t     = pwt + CCH*CCH;                    // 96*192 bf16
    bf16*  oconv   = w1t + GH*CCH;                     // BQ*192*HWP bf16 (25.2 MB)

    // 0. weight convert
    wcvt_kernel<<<dim3(432), 256, 0, stream>>>(qkv_w, qwt, proj_w, pwt, gate_w1, w1t);
    // 1. x -> xt bf16 [b][p][192]
    xcast_kernel<<<dim3(HWP/64, BQ), 256, 0, stream>>>(x, slotC);
    // 2. qkv + gate fused via MFMA (shared A registers) -> bufA + 512 gate partials
    mfma_qkv_gate_kernel<<<dim3(HWP/128, BQ), 256, 0, stream>>>(
        slotC, qwt, bufA, w1t, gate_b1, gate_w2, gate_b2, gparts);
    // 3. depthwise 3x3 (vectorized bf16 staging)
    dw3x3_kernel<<<dim3(16, C3, BQ), 256, 0, stream>>>(bufA, qkv_dw_w, qkv_dw);
    // 4. fc mixing (16 px/block, reuses bufA as f9s)
    fc9_kernel<<<dim3((BQ*HWP)/16), 256, 0, stream>>>(qkv_dw, fc_w, fc_b, bufA);
    // 5. grouped dep conv -> bf16 out_conv in ws
    depconv_kernel<<<dim3(16, 48, BQ), 256, 0, stream>>>(bufA, dep_w, dep_b, oconv);
    // 6. QK^T partials via MFMA + fused q/k sum-of-squares
    attn_dot_kernel<<<dim3(16,16), 256, 0, stream>>>(qkv_dw, attn_partial, qkssq);
    // 7a. parallel partial reduction -> amat (bit-identical ps order)
    attn_reduce_kernel<<<dim3(16,9), 256, 0, stream>>>(attn_partial, amatbuf);
    // 7b. finalize: norms, dynamic-k mask, softmax
    attn_finalize_kernel<<<dim3(16), 256, 0, stream>>>(amatbuf, qkssq, temp, gparts, Abuf);
    // 8. PV -> out_attnT [b][p][192], 64 pixel-partitions (4 blocks/CU)
    attn_out_kernel<<<dim3(16,64), 256, 0, stream>>>(Abuf, qkv_dw, slotC);
    // 9. proj via MFMA + add bf16 out_conv -> single f32 store to d_out
    mfma_projf_kernel<<<dim3(HWP/128, CCH/64, BQ), 256, 0, stream>>>(slotC, pwt, oconv, out);
}

// Round 24
// 418.170 us; speedup vs baseline: 1.1729x; 1.1612x over previous
//
#include <hip/hip_runtime.h>
#include <hip/hip_bf16.h>
#include <math.h>

typedef __hip_bfloat16 bf16;
typedef __attribute__((ext_vector_type(8))) short short8v;
typedef __attribute__((ext_vector_type(4))) float f32x4;

#define BQ 4
#define CCH 192
#define C3 576
#define HWP 16384
#define NHEADS 4
#define CPG 48
#define GH 96

static __device__ __forceinline__ float b2f(bf16 v){ return __bfloat162float(v); }
static __device__ __forceinline__ bf16 f2b(float v){ return __float2bfloat16(v); }
static __device__ __forceinline__ float us2f(unsigned short u){
    union { unsigned u32; float f; } cv; cv.u32 = ((unsigned)u) << 16; return cv.f;
}

// ---------------- x -> xt bf16 transposed [b][p][192] --------------------------------
__global__ __launch_bounds__(256) void xcast_kernel(const float* __restrict__ x,
                                                    bf16* __restrict__ xt)
{
    __shared__ bf16 tile[64][198];
    int t = threadIdx.x;
    int p0 = blockIdx.x * 64;
    int b  = blockIdx.y;
    const float* xb = x + (size_t)b*CCH*HWP;
    #pragma unroll 4
    for (int i = 0; i < 48; ++i) {    // 12288 scalars = 64 px x 192 ch
        int lin = i*256 + t;
        int cc = lin >> 6, pp = lin & 63;
        tile[pp][cc] = f2b(xb[(size_t)cc*HWP + p0 + pp]);
    }
    __syncthreads();
    bf16* dst = xt + ((size_t)b*HWP + p0)*CCH;
    #pragma unroll 4
    for (int i = 0; i < 12; ++i) {    // 3072 ushort4 groups
        int lin = i*256 + t;
        int pp = lin / 48, ch = lin % 48;
        ushort2 u0 = *reinterpret_cast<ushort2*>(&tile[pp][ch*4]);
        ushort2 u1 = *reinterpret_cast<ushort2*>(&tile[pp][ch*4+2]);
        ushort4 v; v.x=u0.x; v.y=u0.y; v.z=u1.x; v.w=u1.y;
        *reinterpret_cast<ushort4*>(dst + (size_t)pp*CCH + ch*4) = v;
    }
}

// ---------------- weights f32 -> bf16 ------------------------------------------------
__global__ void wcvt_kernel(const float* __restrict__ qw, bf16* __restrict__ qwt,
                            const float* __restrict__ pw, bf16* __restrict__ pwt,
                            const float* __restrict__ g1w, bf16* __restrict__ w1t)
{
    int i = blockIdx.x*256 + threadIdx.x;
    if (i < C3*CCH)  qwt[i] = f2b(qw[i]);
    if (i < CCH*CCH) pwt[i] = f2b(pw[i]);
    if (i < GH*CCH)  w1t[i] = f2b(g1w[i]);
}

// ---------------- qkv MFMA GEMM + fused gate (shares A registers) --------------------
__global__ __launch_bounds__(256) void mfma_qkv_gate_kernel(const bf16* __restrict__ xtp,
        const bf16* __restrict__ Wb, bf16* __restrict__ outb,
        const bf16* __restrict__ w1b, const float* __restrict__ b1,
        const float* __restrict__ w2, const float* __restrict__ b2v,
        float* __restrict__ partials)
{
    int t = threadIdx.x;
    int w = t >> 6, l = t & 63;
    int lm = l & 15, lk = l >> 4;
    int p0 = blockIdx.x * 128;
    int b  = blockIdx.y;
    const bf16* xb = xtp + ((size_t)b*HWP + p0 + w*32)*CCH;
    const short8v* a0p = reinterpret_cast<const short8v*>(xb + (size_t)lm*CCH) + lk;
    const short8v* a1p = reinterpret_cast<const short8v*>(xb + (size_t)(16+lm)*CCH) + lk;
    short8v a0[6], a1[6];
    #pragma unroll
    for (int kc = 0; kc < 6; ++kc) { a0[kc] = a0p[kc*4]; a1[kc] = a1p[kc*4]; }
    int pbase = p0 + w*32 + lk*4;
    // ---- phase 1: qkv ----
    for (int ot = 0; ot < 9; ++ot) {
        int o0 = ot*64;
        const short8v* bp[4];
        #pragma unroll
        for (int ni = 0; ni < 4; ++ni)
            bp[ni] = reinterpret_cast<const short8v*>(Wb + (size_t)(o0 + ni*16 + lm)*CCH) + lk;
        f32x4 acc[2][4];
        #pragma unroll
        for (int mi = 0; mi < 2; ++mi)
            #pragma unroll
            for (int ni = 0; ni < 4; ++ni) acc[mi][ni] = (f32x4){0.f,0.f,0.f,0.f};
        #pragma unroll
        for (int kc = 0; kc < 6; ++kc) {
            #pragma unroll
            for (int ni = 0; ni < 4; ++ni) {
                short8v bb = bp[ni][kc*4];
                acc[0][ni] = __builtin_amdgcn_mfma_f32_16x16x32_bf16(a0[kc], bb, acc[0][ni], 0,0,0);
                acc[1][ni] = __builtin_amdgcn_mfma_f32_16x16x32_bf16(a1[kc], bb, acc[1][ni], 0,0,0);
            }
        }
        #pragma unroll
        for (int mi = 0; mi < 2; ++mi)
            #pragma unroll
            for (int ni = 0; ni < 4; ++ni) {
                union { bf16 h[4]; uint2 u; } pk;
                #pragma unroll
                for (int r = 0; r < 4; ++r) pk.h[r] = f2b(acc[mi][ni][r]);
                size_t base = ((size_t)b*C3 + o0 + ni*16 + lm)*HWP + pbase + mi*16;
                *reinterpret_cast<uint2*>(outb + base) = pk.u;
            }
    }
    // ---- phase 2: gate stage1 (reuses a0/a1) ----
    const short8v* gp[6];
    #pragma unroll
    for (int ni = 0; ni < 6; ++ni)
        gp[ni] = reinterpret_cast<const short8v*>(w1b + (size_t)(ni*16 + lm)*CCH) + lk;
    f32x4 gacc[2][6];
    #pragma unroll
    for (int mi = 0; mi < 2; ++mi)
        #pragma unroll
        for (int ni = 0; ni < 6; ++ni) gacc[mi][ni] = (f32x4){0.f,0.f,0.f,0.f};
    #pragma unroll
    for (int kc = 0; kc < 6; ++kc) {
        #pragma unroll
        for (int ni = 0; ni < 6; ++ni) {
            short8v bb = gp[ni][kc*4];
            gacc[0][ni] = __builtin_amdgcn_mfma_f32_16x16x32_bf16(a0[kc], bb, gacc[0][ni], 0,0,0);
            gacc[1][ni] = __builtin_amdgcn_mfma_f32_16x16x32_bf16(a1[kc], bb, gacc[1][ni], 0,0,0);
        }
    }
    float b1v[6], w2v[6];
    #pragma unroll
    for (int ni = 0; ni < 6; ++ni) { b1v[ni] = b1[ni*16+lm]; w2v[ni] = w2[ni*16+lm]; }
    float bias2 = b2v[0];
    float sg_sum = 0.f;
    #pragma unroll
    for (int mi = 0; mi < 2; ++mi)
        #pragma unroll
        for (int r = 0; r < 4; ++r) {
            float part = 0.f;
            #pragma unroll
            for (int ni = 0; ni < 6; ++ni)
                part += w2v[ni] * fmaxf(gacc[mi][ni][r] + b1v[ni], 0.f);
            part += __shfl_xor(part, 1);
            part += __shfl_xor(part, 2);
            part += __shfl_xor(part, 4);
            part += __shfl_xor(part, 8);
            if (lm == 0) sg_sum += 1.f / (1.f + expf(-(part + bias2)));
        }
    __shared__ float red[256];
    red[t] = sg_sum; __syncthreads();
    for (int st = 128; st > 0; st >>= 1) { if (t < st) red[t] += red[t+st]; __syncthreads(); }
    if (t == 0) partials[blockIdx.y*128 + blockIdx.x] = red[0];
}

// ---------------- proj MFMA GEMM: LDS epilogue + add bf16 out_conv -> f32 out --------
__global__ __launch_bounds__(256) void mfma_projf_kernel(const bf16* __restrict__ xtp,
        const bf16* __restrict__ Wb, const bf16* __restrict__ oconv, float* __restrict__ outf)
{
    __shared__ float epf[64][133];
    int t = threadIdx.x;
    int w = t >> 6, l = t & 63;
    int lm = l & 15, lk = l >> 4;
    int p0 = blockIdx.x * 128;
    int o0 = blockIdx.y * 64;
    int b  = blockIdx.z;
    const bf16* xb = xtp + ((size_t)b*HWP + p0 + w*32)*CCH;
    const short8v* a0p = reinterpret_cast<const short8v*>(xb + (size_t)lm*CCH) + lk;
    const short8v* a1p = reinterpret_cast<const short8v*>(xb + (size_t)(16+lm)*CCH) + lk;
    const short8v* bp[4];
    #pragma unroll
    for (int ni = 0; ni < 4; ++ni)
        bp[ni] = reinterpret_cast<const short8v*>(Wb + (size_t)(o0 + ni*16 + lm)*CCH) + lk;
    f32x4 acc[2][4];
    #pragma unroll
    for (int mi = 0; mi < 2; ++mi)
        #pragma unroll
        for (int ni = 0; ni < 4; ++ni) acc[mi][ni] = (f32x4){0.f,0.f,0.f,0.f};
    #pragma unroll
    for (int kc = 0; kc < 6; ++kc) {          // K = 192
        short8v a0 = a0p[kc*4];
        short8v a1 = a1p[kc*4];
        #pragma unroll
        for (int ni = 0; ni < 4; ++ni) {
            short8v bb = bp[ni][kc*4];
            acc[0][ni] = __builtin_amdgcn_mfma_f32_16x16x32_bf16(a0, bb, acc[0][ni], 0,0,0);
            acc[1][ni] = __builtin_amdgcn_mfma_f32_16x16x32_bf16(a1, bb, acc[1][ni], 0,0,0);
        }
    }
    #pragma unroll
    for (int mi = 0; mi < 2; ++mi)
        #pragma unroll
        for (int ni = 0; ni < 4; ++ni)
            #pragma unroll
            for (int r = 0; r < 4; ++r)
                epf[ni*16 + lm][w*32 + mi*16 + lk*4 + r] = acc[mi][ni][r];
    __syncthreads();
    #pragma unroll 4
    for (int i = 0; i < 16; ++i) {
        int lin = i*256 + t;
        int ol = lin >> 6, pc = (lin & 63)*2;
        float v0 = epf[ol][pc], v1 = epf[ol][pc+1];
        size_t base = ((size_t)b*CCH + o0 + ol)*HWP + p0 + pc;
        unsigned u = *reinterpret_cast<const unsigned*>(oconv + base);
        float2 res;
        res.x = v0 + us2f((unsigned short)(u & 0xffffu));
        res.y = v1 + us2f((unsigned short)(u >> 16));
        *reinterpret_cast<float2*>(outf + base) = res;
    }
}

// ---------------- depthwise 3x3, bf16 LDS + vectorized staging -----------------------
__global__ __launch_bounds__(256) void dw3x3_kernel(const bf16* __restrict__ in,
        const float* __restrict__ w, bf16* __restrict__ out)
{
    __shared__ bf16 pl[10][144];      // 2880 B
    int t = threadIdx.x;
    int y0 = blockIdx.x * 8;
    int ch = blockIdx.y;
    int b  = blockIdx.z;
    const bf16* base = in + ((size_t)b*C3 + ch)*HWP;
    if (t < 80) {
        int row = t >> 3, q = t & 7;
        int col = (q < 2) ? (2*q) : (132 + 2*(q-2));
        *reinterpret_cast<unsigned*>(&pl[row][col]) = 0u;
    }
    for (int idx = t; idx < 320; idx += 256) {
        int row = idx >> 5, j = idx & 31;
        int yy = y0 + row - 1;
        ushort4 v = {0,0,0,0};
        if (yy >= 0 && yy < 128)
            v = *reinterpret_cast<const ushort4*>(base + yy*128 + 4*j);
        *reinterpret_cast<ushort4*>(&pl[row][4 + 4*j]) = v;
    }
    __syncthreads();
    const float* wz = w + ch*27 + 9;
    float wk[9];
    #pragma unroll
    for (int k = 0; k < 9; ++k) wk[k] = wz[k];
    int ty = t >> 5;
    int x0 = (t & 31) * 4;
    float acc[4] = {0,0,0,0};
    #pragma unroll
    for (int r = 0; r < 3; ++r) {
        const bf16* row = &pl[ty+r][0];
        unsigned short um = *reinterpret_cast<const unsigned short*>(row + x0 + 3);
        ushort4 u4 = *reinterpret_cast<const ushort4*>(row + x0 + 4);
        unsigned up = *reinterpret_cast<const unsigned*>(row + x0 + 8);
        float vals[6];
        vals[0] = us2f(um);
        vals[1] = us2f(u4.x); vals[2] = us2f(u4.y); vals[3] = us2f(u4.z); vals[4] = us2f(u4.w);
        vals[5] = us2f((unsigned short)(up & 0xffffu));
        #pragma unroll
        for (int px = 0; px < 4; ++px)
            acc[px] += wk[r*3+0]*vals[px] + wk[r*3+1]*vals[px+1] + wk[r*3+2]*vals[px+2];
    }
    bf16 tmp[4];
    #pragma unroll
    for (int px = 0; px < 4; ++px) tmp[px] = f2b(acc[px]);
    bf16* ob = out + ((size_t)b*C3 + ch)*HWP + (size_t)(y0+ty)*128 + x0;
    *reinterpret_cast<uint2*>(ob) = *reinterpret_cast<uint2*>(tmp);
}

// ---------------- fc mixing: 16 px per block (33 KB LDS -> 4 blocks/CU) --------------
__global__ void fc9_kernel(const bf16* __restrict__ qkv, const float* __restrict__ fcw,
                           const float* __restrict__ fcb, bf16* __restrict__ f9s)
{
    __shared__ bf16 raw[16*576];      // 18432 B
    __shared__ bf16 f9t[432*16];      // 13824 B
    __shared__ float fw[9][12];
    __shared__ float fb[9];
    int t = threadIdx.x;
    int blk = blockIdx.x;
    int b = blk >> 10;                // 1024 blocks per batch, 16 px each
    int n0 = (blk & 1023) * 16;
    if (t < 108) fw[t/12][t%12] = fcw[t];
    if (t < 9)   fb[t] = fcb[t];
    const uint4* s4 = reinterpret_cast<const uint4*>(qkv + (size_t)b*C3*HWP + (size_t)n0*576);
    uint4* d4 = reinterpret_cast<uint4*>(raw);
    for (int idx = t; idx < 1152; idx += 256) d4[idx] = s4[idx];
    __syncthreads();
    #pragma unroll
    for (int s = 0; s < 3; ++s) {
        int q = t + s*256;            // 768 (cc,n) pairs
        int cc = q % 48, n = q / 48;
        float acc[9];
        #pragma unroll
        for (int o = 0; o < 9; ++o) acc[o] = fb[o];
        #pragma unroll
        for (int g = 0; g < 12; ++g) {
            float v = b2f(raw[n*576 + g*48 + cc]);
            #pragma unroll
            for (int o = 0; o < 9; ++o) acc[o] += fw[o][g]*v;
        }
        #pragma unroll
        for (int o = 0; o < 9; ++o) f9t[(cc*9+o)*16 + n] = f2b(acc[o]);
    }
    __syncthreads();
    bf16* dst = f9s + (size_t)b*432*HWP + n0;
    for (int idx = t; idx < 432*16; idx += 256) {
        int r = idx >> 4, m = idx & 15;
        dst[(size_t)r*HWP + m] = f9t[idx];
    }
}

// ---------------- grouped 3x3 dep conv -> bf16 out_conv in ws ------------------------
__global__ __launch_bounds__(256) void depconv_kernel(const bf16* __restrict__ f9s,
        const float* __restrict__ depw, const float* __restrict__ depb, bf16* __restrict__ oconv)
{
    __shared__ bf16 pl[9][10][144];   // col = x + 4; 25920 B
    __shared__ float wl[4][84];
    int t = threadIdx.x;
    int y0 = blockIdx.x * 8;
    int gr = blockIdx.y;
    int b  = blockIdx.z;
    const bf16* base = f9s + ((size_t)b*432 + (size_t)gr*9)*HWP;
    for (int idx = t; idx < 4*81; idx += 256) {
        int o = idx / 81, k = idx - o*81;
        int p = k / 9, rk = k - p*9;
        wl[o][k] = depw[(size_t)(gr*4+o)*243 + p*27 + 9 + rk];
    }
    for (int idx = t; idx < 720; idx += 256) {
        int pr = idx >> 3, q = idx & 7;
        int p = pr / 10, row = pr - p*10;
        int col = (q < 2) ? (2*q) : (132 + 2*(q-2));
        *reinterpret_cast<unsigned*>(&pl[p][row][col]) = 0u;
    }
    for (int idx = t; idx < 2880; idx += 256) {
        int p = idx / 320;
        int rem = idx - p*320;
        int row = rem >> 5, j = rem & 31;
        int yy = y0 + row - 1;
        ushort4 v = {0,0,0,0};
        if (yy >= 0 && yy < 128)
            v = *reinterpret_cast<const ushort4*>(base + (size_t)p*HWP + yy*128 + 4*j);
        *reinterpret_cast<ushort4*>(&pl[p][row][4 + 4*j]) = v;
    }
    __syncthreads();
    int ty = t >> 5;
    int x0 = (t & 31) * 4;
    float acc[4][4];
    #pragma unroll
    for (int o = 0; o < 4; ++o) {
        float bv = depb[gr*4+o];
        acc[o][0]=bv; acc[o][1]=bv; acc[o][2]=bv; acc[o][3]=bv;
    }
    #pragma unroll
    for (int p = 0; p < 9; ++p) {
        #pragma unroll
        for (int r = 0; r < 3; ++r) {
            const bf16* row = &pl[p][ty+r][0];
            unsigned short um = *reinterpret_cast<const unsigned short*>(row + x0 + 3);
            ushort4 u4 = *reinterpret_cast<const ushort4*>(row + x0 + 4);
            unsigned up = *reinterpret_cast<const unsigned*>(row + x0 + 8);
            float vals[6];
            vals[0] = us2f(um);
            vals[1] = us2f(u4.x); vals[2] = us2f(u4.y); vals[3] = us2f(u4.z); vals[4] = us2f(u4.w);
            vals[5] = us2f((unsigned short)(up & 0xffffu));
            #pragma unroll
            for (int o = 0; o < 4; ++o) {
                float w0 = wl[o][p*9+r*3+0];
                float w1 = wl[o][p*9+r*3+1];
                float w2 = wl[o][p*9+r*3+2];
                #pragma unroll
                for (int px = 0; px < 4; ++px)
                    acc[o][px] += w0*vals[px] + w1*vals[px+1] + w2*vals[px+2];
            }
        }
    }
    bf16* ob = oconv + ((size_t)b*192 + (size_t)gr*4)*HWP + (size_t)(y0+ty)*128 + x0;
    #pragma unroll
    for (int o = 0; o < 4; ++o) {
        union { bf16 h[4]; uint2 u; } pk;
        #pragma unroll
        for (int px = 0; px < 4; ++px) pk.h[px] = f2b(acc[o][px]);
        *reinterpret_cast<uint2*>(ob + (size_t)o*HWP) = pk.u;
    }
}

// ---------------- QK^T partials via MFMA + fused q/k row sum-of-squares --------------
__global__ __launch_bounds__(256) void attn_dot_kernel(const bf16* __restrict__ qkv,
        float* __restrict__ partial, float* __restrict__ ssqbuf)
{
    __shared__ float ldsred[4][2304];   // 36864 B
    __shared__ float sqq[4][48];
    __shared__ float sqk[4][48];
    int bh = blockIdx.x, ps = blockIdx.y;
    int b = bh >> 2, h = bh & 3;
    int t = threadIdx.x;
    int w = t >> 6, l = t & 63;
    int lm = l & 15, lk = l >> 4;
    int K0 = ps*1024 + w*256;
    const bf16* qbase = qkv + ((size_t)b*C3 + h*48) * HWP + K0;
    const bf16* kbase = qbase + (size_t)192*HWP;
    const short8v* ap[3];
    const short8v* bp[3];
    #pragma unroll
    for (int mi = 0; mi < 3; ++mi)
        ap[mi] = reinterpret_cast<const short8v*>(qbase + (size_t)(mi*16+lm)*HWP) + lk;
    #pragma unroll
    for (int ni = 0; ni < 3; ++ni)
        bp[ni] = reinterpret_cast<const short8v*>(kbase + (size_t)(ni*16+lm)*HWP) + lk;
    f32x4 acc[3][3];
    #pragma unroll
    for (int mi = 0; mi < 3; ++mi)
        #pragma unroll
        for (int ni = 0; ni < 3; ++ni) acc[mi][ni] = (f32x4){0.f,0.f,0.f,0.f};
    float ssqa[3] = {0.f,0.f,0.f};
    float ssqb[3] = {0.f,0.f,0.f};
    #pragma unroll
    for (int kc = 0; kc < 8; ++kc) {    // 256 = 8 x 32
        short8v a[3], bb[3];
        #pragma unroll
        for (int mi = 0; mi < 3; ++mi) a[mi] = ap[mi][kc*4];
        #pragma unroll
        for (int ni = 0; ni < 3; ++ni) bb[ni] = bp[ni][kc*4];
        #pragma unroll
        for (int mi = 0; mi < 3; ++mi)
            #pragma unroll
            for (int ni = 0; ni < 3; ++ni)
                acc[mi][ni] = __builtin_amdgcn_mfma_f32_16x16x32_bf16(a[mi], bb[ni], acc[mi][ni], 0,0,0);
        #pragma unroll
        for (int mi = 0; mi < 3; ++mi)
            #pragma unroll
            for (int j = 0; j < 8; ++j) {
                float va = us2f((unsigned short)a[mi][j]);
                float vb = us2f((unsigned short)bb[mi][j]);
                ssqa[mi] += va*va;
                ssqb[mi] += vb*vb;
            }
    }
    #pragma unroll
    for (int mi = 0; mi < 3; ++mi) {
        float va = ssqa[mi];
        va += __shfl_xor(va, 16); va += __shfl_xor(va, 32);
        float vb = ssqb[mi];
        vb += __shfl_xor(vb, 16); vb += __shfl_xor(vb, 32);
        if (lk == 0) { sqq[w][mi*16+lm] = va; sqk[w][mi*16+lm] = vb; }
    }
    #pragma unroll
    for (int mi = 0; mi < 3; ++mi)
        #pragma unroll
        for (int ni = 0; ni < 3; ++ni)
            #pragma unroll
            for (int r = 0; r < 4; ++r)
                ldsred[w][(mi*16 + lk*4 + r)*48 + ni*16 + lm] = acc[mi][ni][r];
    __syncthreads();
    float* dst = partial + ((size_t)bh*16 + ps)*2304;
    for (int idx = t; idx < 2304; idx += 256)
        dst[idx] = ldsred[0][idx] + ldsred[1][idx] + ldsred[2][idx] + ldsred[3][idx];
    if (t < 96) {
        float s = (t < 48) ? (sqq[0][t] + sqq[1][t] + sqq[2][t] + sqq[3][t])
                           : (sqk[0][t-48] + sqk[1][t-48] + sqk[2][t-48] + sqk[3][t-48]);
        ssqbuf[((size_t)bh*16 + ps)*96 + t] = s;
    }
}

// ---------------- attn partial reduction: 1 amat entry per thread --------------------
__global__ __launch_bounds__(256) void attn_reduce_kernel(const float* __restrict__ partial,
                                                          float* __restrict__ amat)
{
    int bh = blockIdx.x;
    int idx = blockIdx.y*256 + threadIdx.x;   // 9*256 = 2304
    const float* pb = partial + (size_t)bh*16*2304 + idx;
    float s = 0.f;
    #pragma unroll
    for (int ps = 0; ps < 16; ++ps) s += pb[ps*2304];
    amat[(size_t)bh*2304 + idx] = s;
}

// ---------------- finalize attention: all-LDS (no scratch arrays) --------------------
// f32 expression/summation orders preserved (bit-identical to scratch version).
__global__ __launch_bounds__(256) void attn_finalize_kernel(const float* __restrict__ amat,
        const float* __restrict__ ssqbuf, const float* __restrict__ temp,
        const float* __restrict__ gparts, float* __restrict__ A)
{
    __shared__ float sa[2304];     // scaled logits
    __shared__ float em[2304];     // keep flag, then exp values
    __shared__ float qinv[48];
    __shared__ float kinv[48];
    __shared__ float dksh;
    int bh = blockIdx.x; int h = bh & 3;
    int t = threadIdx.x;
    if (t == 0) {
        float gs = 0.f;
        for (int k = 0; k < 512; ++k) gs += gparts[k];
        dksh = floorf(48.f * (gs / 65536.f));
    }
    if (t < 96) {
        float s = 0.f;
        for (int ps = 0; ps < 16; ++ps) s += ssqbuf[((size_t)bh*16 + ps)*96 + t];
        float inv = 1.f / fmaxf(sqrtf(s), 1e-12f);
        if (t < 48) qinv[t] = inv; else kinv[t-48] = inv;
    }
    __syncthreads();
    float tm = temp[h];
    const float* ab = amat + (size_t)bh*2304;
    for (int idx = t; idx < 2304; idx += 256) {
        int i = idx / 48, j = idx - i*48;
        sa[idx] = ab[idx] * qinv[i] * kinv[j] * tm;   // same mult order as before
    }
    __syncthreads();
    int dk = (int)dksh;
    if (dk > 48) dk = 48;
    for (int idx = t; idx < 2304; idx += 256) {
        int i = idx / 48, j = idx - i*48;
        float aj = sa[idx];
        const float* row = &sa[i*48];
        int r = 0;
        for (int l = 0; l < 48; ++l) {
            float al = row[l];
            r += (al > aj) || (al == aj && l < j);
        }
        em[idx] = (r < dk) ? 1.f : 0.f;
    }
    __syncthreads();
    if (t >= 48) return;
    int i = t;
    const float* row = &sa[i*48];
    float* erow = &em[i*48];
    float m = -1e30f;
    for (int j = 0; j < 48; ++j) if (erow[j] != 0.f) m = fmaxf(m, row[j]);
    float sum = 0.f;
    for (int j = 0; j < 48; ++j) {
        float e = (erow[j] != 0.f) ? expf(row[j] - m) : 0.f;
        erow[j] = e;
        sum += e;
    }
    float inv = 1.f / sum;
    float* dst = A + (size_t)bh*2304 + i*48;
    for (int j = 0; j < 48; ++j) dst[j] = erow[j]*inv;
}

// ---------------- PV: writes out_attn TRANSPOSED [b][p][192]; 4 chunks/block ---------
__global__ void attn_out_kernel(const float* __restrict__ A, const bf16* __restrict__ qkv,
                                bf16* __restrict__ out_attnT)
{
    int bh = blockIdx.x, ps = blockIdx.y;      // ps in 0..63 -> 256-px partition
    int b = bh >> 2, h = bh & 3;
    int t = threadIdx.x;
    __shared__ float As[48*48];
    __shared__ float vs[48][64];
    for (int idx = t; idx < 2304; idx += 256) As[idx] = A[(size_t)bh*2304 + idx];
    const bf16* vbase = qkv + ((size_t)b*C3 + 384 + h*48) * HWP;
    bf16* oT = out_attnT + (size_t)b*HWP*CCH;
    int pp = t & 63, ig = t >> 6;
    for (int chunk = 0; chunk < 4; ++chunk) {
        int pc = ps*256 + chunk*64;
        __syncthreads();
        #pragma unroll
        for (int s = 0; s < 12; ++s) {
            int idx = t + s*256;
            int r = idx >> 6, c = idx & 63;
            vs[r][c] = b2f(vbase[(size_t)r*HWP + pc + c]);
        }
        __syncthreads();
        float acc[12] = {0,0,0,0,0,0,0,0,0,0,0,0};
        for (int j = 0; j < 48; ++j) {
            float vv = vs[j][pp];
            #pragma unroll
            for (int ii = 0; ii < 12; ++ii) acc[ii] += As[(ig*12+ii)*48 + j]*vv;
        }
        bf16* od = oT + (size_t)(pc+pp)*CCH + h*48 + ig*12;
        #pragma unroll
        for (int ii = 0; ii < 12; ++ii)
            od[ii] = f2b(acc[ii]);
    }
}

extern "C" void kernel_launch(void* const* d_in, const int* in_sizes, int n_in,
                              void* d_out, int out_size, void* d_ws, size_t ws_size,
                              hipStream_t stream)
{
    const float* x        = (const float*)d_in[0];
    const float* temp     = (const float*)d_in[1];
    const float* qkv_w    = (const float*)d_in[2];
    const float* qkv_dw_w = (const float*)d_in[3];
    const float* proj_w   = (const float*)d_in[4];
    const float* fc_w     = (const float*)d_in[5];
    const float* fc_b     = (const float*)d_in[6];
    const float* dep_w    = (const float*)d_in[7];
    const float* dep_b    = (const float*)d_in[8];
    const float* gate_w1  = (const float*)d_in[9];
    const float* gate_b1  = (const float*)d_in[10];
    const float* gate_w2  = (const float*)d_in[11];
    const float* gate_b2  = (const float*)d_in[12];
    float* out = (float*)d_out;
    char* ws = (char*)d_ws;

    const size_t SZ_A = (size_t)BQ*C3*HWP*2;           // 75,497,472 B
    bf16* bufA   = (bf16*)(ws);                        // qkv (MFMA out), then f9s
    bf16* qkv_dw = (bf16*)(ws + SZ_A);
    bf16* slotC  = (bf16*)(ws + 2*SZ_A);               // xt, then out_attnT (25.2 MB)
    char* tail   = ws + 2*SZ_A + (size_t)BQ*HWP*CCH*2;
    float* attn_partial = (float*)tail;                // 16*16*2304 f32
    float* Abuf    = attn_partial + 16*16*2304;        // 16*2304
    float* amatbuf = Abuf + 16*2304;                   // 16*2304
    float* qkssq   = amatbuf + 16*2304;                // 16*16*96 f32
    float* gparts  = qkssq + 16*16*96;                 // 512 f32
    bf16*  qwt     = (bf16*)(gparts + 512);            // 576*192 bf16
    bf16*  pwt     = qwt + C3*CCH;                     // 192*192 bf16
    bf16*  w1t     = pwt + CCH*CCH;                    // 96*192 bf16
    bf16*  oconv   = w1t + GH*CCH;                     // BQ*192*HWP bf16 (25.2 MB)

    // 0. weight convert
    wcvt_kernel<<<dim3(432), 256, 0, stream>>>(qkv_w, qwt, proj_w, pwt, gate_w1, w1t);
    // 1. x -> xt bf16 [b][p][192]
    xcast_kernel<<<dim3(HWP/64, BQ), 256, 0, stream>>>(x, slotC);
    // 2. qkv + gate fused via MFMA (shared A registers) -> bufA + 512 gate partials
    mfma_qkv_gate_kernel<<<dim3(HWP/128, BQ), 256, 0, stream>>>(
        slotC, qwt, bufA, w1t, gate_b1, gate_w2, gate_b2, gparts);
    // 3. depthwise 3x3 (vectorized bf16 staging)
    dw3x3_kernel<<<dim3(16, C3, BQ), 256, 0, stream>>>(bufA, qkv_dw_w, qkv_dw);
    // 4. fc mixing (16 px/block, reuses bufA as f9s)
    fc9_kernel<<<dim3((BQ*HWP)/16), 256, 0, stream>>>(qkv_dw, fc_w, fc_b, bufA);
    // 5. grouped dep conv -> bf16 out_conv in ws
    depconv_kernel<<<dim3(16, 48, BQ), 256, 0, stream>>>(bufA, dep_w, dep_b, oconv);
    // 6. QK^T partials via MFMA + fused q/k sum-of-squares
    attn_dot_kernel<<<dim3(16,16), 256, 0, stream>>>(qkv_dw, attn_partial, qkssq);
    // 7a. parallel partial reduction -> amat (bit-identical ps order)
    attn_reduce_kernel<<<dim3(16,9), 256, 0, stream>>>(attn_partial, amatbuf);
    // 7b. finalize (all-LDS): norms, dynamic-k mask, softmax
    attn_finalize_kernel<<<dim3(16), 256, 0, stream>>>(amatbuf, qkssq, temp, gparts, Abuf);
    // 8. PV -> out_attnT [b][p][192], 64 pixel-partitions (4 blocks/CU)
    attn_out_kernel<<<dim3(16,64), 256, 0, stream>>>(Abuf, qkv_dw, slotC);
    // 9. proj via MFMA + add bf16 out_conv -> single f32 store to d_out
    mfma_projf_kernel<<<dim3(HWP/128, CCH/64, BQ), 256, 0, stream>>>(slotC, pwt, oconv, out);
}

// Round 25
// 396.718 us; speedup vs baseline: 1.2363x; 1.0541x over previous
//
#include <hip/hip_runtime.h>
#include <hip/hip_bf16.h>
#include <math.h>

typedef __hip_bfloat16 bf16;
typedef __attribute__((ext_vector_type(8))) short short8v;
typedef __attribute__((ext_vector_type(4))) float f32x4;
typedef __attribute__((ext_vector_type(2))) float f32x2;

#define BQ 4
#define CCH 192
#define C3 576
#define HWP 16384
#define NHEADS 4
#define CPG 48
#define GH 96

static __device__ __forceinline__ float b2f(bf16 v){ return __bfloat162float(v); }
static __device__ __forceinline__ bf16 f2b(float v){ return __float2bfloat16(v); }
static __device__ __forceinline__ float us2f(unsigned short u){
    union { unsigned u32; float f; } cv; cv.u32 = ((unsigned)u) << 16; return cv.f;
}

// ---------------- x -> xt bf16 transposed [b][p][192] --------------------------------
__global__ __launch_bounds__(256) void xcast_kernel(const float* __restrict__ x,
                                                    bf16* __restrict__ xt)
{
    __shared__ bf16 tile[64][198];
    int t = threadIdx.x;
    int p0 = blockIdx.x * 64;
    int b  = blockIdx.y;
    const float* xb = x + (size_t)b*CCH*HWP;
    #pragma unroll 4
    for (int i = 0; i < 48; ++i) {    // 12288 scalars = 64 px x 192 ch
        int lin = i*256 + t;
        int cc = lin >> 6, pp = lin & 63;
        tile[pp][cc] = f2b(xb[(size_t)cc*HWP + p0 + pp]);
    }
    __syncthreads();
    bf16* dst = xt + ((size_t)b*HWP + p0)*CCH;
    #pragma unroll 4
    for (int i = 0; i < 12; ++i) {    // 3072 ushort4 groups
        int lin = i*256 + t;
        int pp = lin / 48, ch = lin % 48;
        ushort2 u0 = *reinterpret_cast<ushort2*>(&tile[pp][ch*4]);
        ushort2 u1 = *reinterpret_cast<ushort2*>(&tile[pp][ch*4+2]);
        ushort4 v; v.x=u0.x; v.y=u0.y; v.z=u1.x; v.w=u1.y;
        *reinterpret_cast<ushort4*>(dst + (size_t)pp*CCH + ch*4) = v;
    }
}

// ---------------- weights f32 -> bf16 ------------------------------------------------
__global__ void wcvt_kernel(const float* __restrict__ qw, bf16* __restrict__ qwt,
                            const float* __restrict__ pw, bf16* __restrict__ pwt,
                            const float* __restrict__ g1w, bf16* __restrict__ w1t)
{
    int i = blockIdx.x*256 + threadIdx.x;
    if (i < C3*CCH)  qwt[i] = f2b(qw[i]);
    if (i < CCH*CCH) pwt[i] = f2b(pw[i]);
    if (i < GH*CCH)  w1t[i] = f2b(g1w[i]);
}

// ---------------- qkv MFMA GEMM + fused gate (shares A registers) --------------------
__global__ __launch_bounds__(256) void mfma_qkv_gate_kernel(const bf16* __restrict__ xtp,
        const bf16* __restrict__ Wb, bf16* __restrict__ outb,
        const bf16* __restrict__ w1b, const float* __restrict__ b1,
        const float* __restrict__ w2, const float* __restrict__ b2v,
        float* __restrict__ partials)
{
    int t = threadIdx.x;
    int w = t >> 6, l = t & 63;
    int lm = l & 15, lk = l >> 4;
    int p0 = blockIdx.x * 128;
    int b  = blockIdx.y;
    const bf16* xb = xtp + ((size_t)b*HWP + p0 + w*32)*CCH;
    const short8v* a0p = reinterpret_cast<const short8v*>(xb + (size_t)lm*CCH) + lk;
    const short8v* a1p = reinterpret_cast<const short8v*>(xb + (size_t)(16+lm)*CCH) + lk;
    short8v a0[6], a1[6];
    #pragma unroll
    for (int kc = 0; kc < 6; ++kc) { a0[kc] = a0p[kc*4]; a1[kc] = a1p[kc*4]; }
    int pbase = p0 + w*32 + lk*4;
    // ---- phase 1: qkv ----
    for (int ot = 0; ot < 9; ++ot) {
        int o0 = ot*64;
        const short8v* bp[4];
        #pragma unroll
        for (int ni = 0; ni < 4; ++ni)
            bp[ni] = reinterpret_cast<const short8v*>(Wb + (size_t)(o0 + ni*16 + lm)*CCH) + lk;
        f32x4 acc[2][4];
        #pragma unroll
        for (int mi = 0; mi < 2; ++mi)
            #pragma unroll
            for (int ni = 0; ni < 4; ++ni) acc[mi][ni] = (f32x4){0.f,0.f,0.f,0.f};
        #pragma unroll
        for (int kc = 0; kc < 6; ++kc) {
            #pragma unroll
            for (int ni = 0; ni < 4; ++ni) {
                short8v bb = bp[ni][kc*4];
                acc[0][ni] = __builtin_amdgcn_mfma_f32_16x16x32_bf16(a0[kc], bb, acc[0][ni], 0,0,0);
                acc[1][ni] = __builtin_amdgcn_mfma_f32_16x16x32_bf16(a1[kc], bb, acc[1][ni], 0,0,0);
            }
        }
        #pragma unroll
        for (int mi = 0; mi < 2; ++mi)
            #pragma unroll
            for (int ni = 0; ni < 4; ++ni) {
                union { bf16 h[4]; uint2 u; } pk;
                #pragma unroll
                for (int r = 0; r < 4; ++r) pk.h[r] = f2b(acc[mi][ni][r]);
                size_t base = ((size_t)b*C3 + o0 + ni*16 + lm)*HWP + pbase + mi*16;
                *reinterpret_cast<uint2*>(outb + base) = pk.u;
            }
    }
    // ---- phase 2: gate stage1 (reuses a0/a1) ----
    const short8v* gp[6];
    #pragma unroll
    for (int ni = 0; ni < 6; ++ni)
        gp[ni] = reinterpret_cast<const short8v*>(w1b + (size_t)(ni*16 + lm)*CCH) + lk;
    f32x4 gacc[2][6];
    #pragma unroll
    for (int mi = 0; mi < 2; ++mi)
        #pragma unroll
        for (int ni = 0; ni < 6; ++ni) gacc[mi][ni] = (f32x4){0.f,0.f,0.f,0.f};
    #pragma unroll
    for (int kc = 0; kc < 6; ++kc) {
        #pragma unroll
        for (int ni = 0; ni < 6; ++ni) {
            short8v bb = gp[ni][kc*4];
            gacc[0][ni] = __builtin_amdgcn_mfma_f32_16x16x32_bf16(a0[kc], bb, gacc[0][ni], 0,0,0);
            gacc[1][ni] = __builtin_amdgcn_mfma_f32_16x16x32_bf16(a1[kc], bb, gacc[1][ni], 0,0,0);
        }
    }
    float b1v[6], w2v[6];
    #pragma unroll
    for (int ni = 0; ni < 6; ++ni) { b1v[ni] = b1[ni*16+lm]; w2v[ni] = w2[ni*16+lm]; }
    float bias2 = b2v[0];
    float sg_sum = 0.f;
    #pragma unroll
    for (int mi = 0; mi < 2; ++mi)
        #pragma unroll
        for (int r = 0; r < 4; ++r) {
            float part = 0.f;
            #pragma unroll
            for (int ni = 0; ni < 6; ++ni)
                part += w2v[ni] * fmaxf(gacc[mi][ni][r] + b1v[ni], 0.f);
            part += __shfl_xor(part, 1);
            part += __shfl_xor(part, 2);
            part += __shfl_xor(part, 4);
            part += __shfl_xor(part, 8);
            if (lm == 0) sg_sum += 1.f / (1.f + expf(-(part + bias2)));
        }
    __shared__ float red[256];
    red[t] = sg_sum; __syncthreads();
    for (int st = 128; st > 0; st >>= 1) { if (t < st) red[t] += red[t+st]; __syncthreads(); }
    if (t == 0) partials[blockIdx.y*128 + blockIdx.x] = red[0];
}

// ---------------- proj MFMA GEMM: LDS epilogue + add bf16 out_conv -> f32 out --------
__global__ __launch_bounds__(256) void mfma_projf_kernel(const bf16* __restrict__ xtp,
        const bf16* __restrict__ Wb, const bf16* __restrict__ oconv, float* __restrict__ outf)
{
    __shared__ float epf[64][133];
    int t = threadIdx.x;
    int w = t >> 6, l = t & 63;
    int lm = l & 15, lk = l >> 4;
    int p0 = blockIdx.x * 128;
    int o0 = blockIdx.y * 64;
    int b  = blockIdx.z;
    const bf16* xb = xtp + ((size_t)b*HWP + p0 + w*32)*CCH;
    const short8v* a0p = reinterpret_cast<const short8v*>(xb + (size_t)lm*CCH) + lk;
    const short8v* a1p = reinterpret_cast<const short8v*>(xb + (size_t)(16+lm)*CCH) + lk;
    const short8v* bp[4];
    #pragma unroll
    for (int ni = 0; ni < 4; ++ni)
        bp[ni] = reinterpret_cast<const short8v*>(Wb + (size_t)(o0 + ni*16 + lm)*CCH) + lk;
    f32x4 acc[2][4];
    #pragma unroll
    for (int mi = 0; mi < 2; ++mi)
        #pragma unroll
        for (int ni = 0; ni < 4; ++ni) acc[mi][ni] = (f32x4){0.f,0.f,0.f,0.f};
    #pragma unroll
    for (int kc = 0; kc < 6; ++kc) {          // K = 192
        short8v a0 = a0p[kc*4];
        short8v a1 = a1p[kc*4];
        #pragma unroll
        for (int ni = 0; ni < 4; ++ni) {
            short8v bb = bp[ni][kc*4];
            acc[0][ni] = __builtin_amdgcn_mfma_f32_16x16x32_bf16(a0, bb, acc[0][ni], 0,0,0);
            acc[1][ni] = __builtin_amdgcn_mfma_f32_16x16x32_bf16(a1, bb, acc[1][ni], 0,0,0);
        }
    }
    #pragma unroll
    for (int mi = 0; mi < 2; ++mi)
        #pragma unroll
        for (int ni = 0; ni < 4; ++ni)
            #pragma unroll
            for (int r = 0; r < 4; ++r)
                epf[ni*16 + lm][w*32 + mi*16 + lk*4 + r] = acc[mi][ni][r];
    __syncthreads();
    #pragma unroll 4
    for (int i = 0; i < 16; ++i) {
        int lin = i*256 + t;
        int ol = lin >> 6, pc = (lin & 63)*2;
        float v0 = epf[ol][pc], v1 = epf[ol][pc+1];
        size_t base = ((size_t)b*CCH + o0 + ol)*HWP + p0 + pc;
        unsigned u = *reinterpret_cast<const unsigned*>(oconv + base);
        float2 res;
        res.x = v0 + us2f((unsigned short)(u & 0xffffu));
        res.y = v1 + us2f((unsigned short)(u >> 16));
        *reinterpret_cast<float2*>(outf + base) = res;
    }
}

// ---------------- depthwise 3x3, bf16 LDS + vectorized staging -----------------------
__global__ __launch_bounds__(256) void dw3x3_kernel(const bf16* __restrict__ in,
        const float* __restrict__ w, bf16* __restrict__ out)
{
    __shared__ bf16 pl[10][144];      // 2880 B
    int t = threadIdx.x;
    int y0 = blockIdx.x * 8;
    int ch = blockIdx.y;
    int b  = blockIdx.z;
    const bf16* base = in + ((size_t)b*C3 + ch)*HWP;
    if (t < 80) {
        int row = t >> 3, q = t & 7;
        int col = (q < 2) ? (2*q) : (132 + 2*(q-2));
        *reinterpret_cast<unsigned*>(&pl[row][col]) = 0u;
    }
    for (int idx = t; idx < 320; idx += 256) {
        int row = idx >> 5, j = idx & 31;
        int yy = y0 + row - 1;
        ushort4 v = {0,0,0,0};
        if (yy >= 0 && yy < 128)
            v = *reinterpret_cast<const ushort4*>(base + yy*128 + 4*j);
        *reinterpret_cast<ushort4*>(&pl[row][4 + 4*j]) = v;
    }
    __syncthreads();
    const float* wz = w + ch*27 + 9;
    float wk[9];
    #pragma unroll
    for (int k = 0; k < 9; ++k) wk[k] = wz[k];
    int ty = t >> 5;
    int x0 = (t & 31) * 4;
    float acc[4] = {0,0,0,0};
    #pragma unroll
    for (int r = 0; r < 3; ++r) {
        const bf16* row = &pl[ty+r][0];
        unsigned short um = *reinterpret_cast<const unsigned short*>(row + x0 + 3);
        ushort4 u4 = *reinterpret_cast<const ushort4*>(row + x0 + 4);
        unsigned up = *reinterpret_cast<const unsigned*>(row + x0 + 8);
        float vals[6];
        vals[0] = us2f(um);
        vals[1] = us2f(u4.x); vals[2] = us2f(u4.y); vals[3] = us2f(u4.z); vals[4] = us2f(u4.w);
        vals[5] = us2f((unsigned short)(up & 0xffffu));
        #pragma unroll
        for (int px = 0; px < 4; ++px)
            acc[px] += wk[r*3+0]*vals[px] + wk[r*3+1]*vals[px+1] + wk[r*3+2]*vals[px+2];
    }
    bf16 tmp[4];
    #pragma unroll
    for (int px = 0; px < 4; ++px) tmp[px] = f2b(acc[px]);
    bf16* ob = out + ((size_t)b*C3 + ch)*HWP + (size_t)(y0+ty)*128 + x0;
    *reinterpret_cast<uint2*>(ob) = *reinterpret_cast<uint2*>(tmp);
}

// ---------------- fc mixing: 16 px per block (33 KB LDS -> 4 blocks/CU) --------------
__global__ void fc9_kernel(const bf16* __restrict__ qkv, const float* __restrict__ fcw,
                           const float* __restrict__ fcb, bf16* __restrict__ f9s)
{
    __shared__ bf16 raw[16*576];      // 18432 B
    __shared__ bf16 f9t[432*16];      // 13824 B
    __shared__ float fw[9][12];
    __shared__ float fb[9];
    int t = threadIdx.x;
    int blk = blockIdx.x;
    int b = blk >> 10;                // 1024 blocks per batch, 16 px each
    int n0 = (blk & 1023) * 16;
    if (t < 108) fw[t/12][t%12] = fcw[t];
    if (t < 9)   fb[t] = fcb[t];
    const uint4* s4 = reinterpret_cast<const uint4*>(qkv + (size_t)b*C3*HWP + (size_t)n0*576);
    uint4* d4 = reinterpret_cast<uint4*>(raw);
    for (int idx = t; idx < 1152; idx += 256) d4[idx] = s4[idx];
    __syncthreads();
    #pragma unroll
    for (int s = 0; s < 3; ++s) {
        int q = t + s*256;            // 768 (cc,n) pairs
        int cc = q % 48, n = q / 48;
        float acc[9];
        #pragma unroll
        for (int o = 0; o < 9; ++o) acc[o] = fb[o];
        #pragma unroll
        for (int g = 0; g < 12; ++g) {
            float v = b2f(raw[n*576 + g*48 + cc]);
            #pragma unroll
            for (int o = 0; o < 9; ++o) acc[o] += fw[o][g]*v;
        }
        #pragma unroll
        for (int o = 0; o < 9; ++o) f9t[(cc*9+o)*16 + n] = f2b(acc[o]);
    }
    __syncthreads();
    bf16* dst = f9s + (size_t)b*432*HWP + n0;
    for (int idx = t; idx < 432*16; idx += 256) {
        int r = idx >> 4, m = idx & 15;
        dst[(size_t)r*HWP + m] = f9t[idx];
    }
}

// ---------------- grouped 3x3 dep conv -> bf16 out_conv in ws ------------------------
__global__ __launch_bounds__(256) void depconv_kernel(const bf16* __restrict__ f9s,
        const float* __restrict__ depw, const float* __restrict__ depb, bf16* __restrict__ oconv)
{
    __shared__ bf16 pl[9][10][144];   // col = x + 4; 25920 B
    __shared__ float wl[4][84];
    int t = threadIdx.x;
    int y0 = blockIdx.x * 8;
    int gr = blockIdx.y;
    int b  = blockIdx.z;
    const bf16* base = f9s + ((size_t)b*432 + (size_t)gr*9)*HWP;
    for (int idx = t; idx < 4*81; idx += 256) {
        int o = idx / 81, k = idx - o*81;
        int p = k / 9, rk = k - p*9;
        wl[o][k] = depw[(size_t)(gr*4+o)*243 + p*27 + 9 + rk];
    }
    for (int idx = t; idx < 720; idx += 256) {
        int pr = idx >> 3, q = idx & 7;
        int p = pr / 10, row = pr - p*10;
        int col = (q < 2) ? (2*q) : (132 + 2*(q-2));
        *reinterpret_cast<unsigned*>(&pl[p][row][col]) = 0u;
    }
    for (int idx = t; idx < 2880; idx += 256) {
        int p = idx / 320;
        int rem = idx - p*320;
        int row = rem >> 5, j = rem & 31;
        int yy = y0 + row - 1;
        ushort4 v = {0,0,0,0};
        if (yy >= 0 && yy < 128)
            v = *reinterpret_cast<const ushort4*>(base + (size_t)p*HWP + yy*128 + 4*j);
        *reinterpret_cast<ushort4*>(&pl[p][row][4 + 4*j]) = v;
    }
    __syncthreads();
    int ty = t >> 5;
    int x0 = (t & 31) * 4;
    float acc[4][4];
    #pragma unroll
    for (int o = 0; o < 4; ++o) {
        float bv = depb[gr*4+o];
        acc[o][0]=bv; acc[o][1]=bv; acc[o][2]=bv; acc[o][3]=bv;
    }
    #pragma unroll
    for (int p = 0; p < 9; ++p) {
        #pragma unroll
        for (int r = 0; r < 3; ++r) {
            const bf16* row = &pl[p][ty+r][0];
            unsigned short um = *reinterpret_cast<const unsigned short*>(row + x0 + 3);
            ushort4 u4 = *reinterpret_cast<const ushort4*>(row + x0 + 4);
            unsigned up = *reinterpret_cast<const unsigned*>(row + x0 + 8);
            float vals[6];
            vals[0] = us2f(um);
            vals[1] = us2f(u4.x); vals[2] = us2f(u4.y); vals[3] = us2f(u4.z); vals[4] = us2f(u4.w);
            vals[5] = us2f((unsigned short)(up & 0xffffu));
            #pragma unroll
            for (int o = 0; o < 4; ++o) {
                float w0 = wl[o][p*9+r*3+0];
                float w1 = wl[o][p*9+r*3+1];
                float w2 = wl[o][p*9+r*3+2];
                #pragma unroll
                for (int px = 0; px < 4; ++px)
                    acc[o][px] += w0*vals[px] + w1*vals[px+1] + w2*vals[px+2];
            }
        }
    }
    bf16* ob = oconv + ((size_t)b*192 + (size_t)gr*4)*HWP + (size_t)(y0+ty)*128 + x0;
    #pragma unroll
    for (int o = 0; o < 4; ++o) {
        union { bf16 h[4]; uint2 u; } pk;
        #pragma unroll
        for (int px = 0; px < 4; ++px) pk.h[px] = f2b(acc[o][px]);
        *reinterpret_cast<uint2*>(ob + (size_t)o*HWP) = pk.u;
    }
}

// ---------------- QK^T partials via MFMA + fused q/k row sum-of-squares --------------
__global__ __launch_bounds__(256) void attn_dot_kernel(const bf16* __restrict__ qkv,
        float* __restrict__ partial, float* __restrict__ ssqbuf)
{
    __shared__ float ldsred[4][2304];   // 36864 B
    __shared__ float sqq[4][48];
    __shared__ float sqk[4][48];
    int bh = blockIdx.x, ps = blockIdx.y;
    int b = bh >> 2, h = bh & 3;
    int t = threadIdx.x;
    int w = t >> 6, l = t & 63;
    int lm = l & 15, lk = l >> 4;
    int K0 = ps*1024 + w*256;
    const bf16* qbase = qkv + ((size_t)b*C3 + h*48) * HWP + K0;
    const bf16* kbase = qbase + (size_t)192*HWP;
    const short8v* ap[3];
    const short8v* bp[3];
    #pragma unroll
    for (int mi = 0; mi < 3; ++mi)
        ap[mi] = reinterpret_cast<const short8v*>(qbase + (size_t)(mi*16+lm)*HWP) + lk;
    #pragma unroll
    for (int ni = 0; ni < 3; ++ni)
        bp[ni] = reinterpret_cast<const short8v*>(kbase + (size_t)(ni*16+lm)*HWP) + lk;
    f32x4 acc[3][3];
    #pragma unroll
    for (int mi = 0; mi < 3; ++mi)
        #pragma unroll
        for (int ni = 0; ni < 3; ++ni) acc[mi][ni] = (f32x4){0.f,0.f,0.f,0.f};
    float ssqa[3] = {0.f,0.f,0.f};
    float ssqb[3] = {0.f,0.f,0.f};
    #pragma unroll
    for (int kc = 0; kc < 8; ++kc) {    // 256 = 8 x 32
        short8v a[3], bb[3];
        #pragma unroll
        for (int mi = 0; mi < 3; ++mi) a[mi] = ap[mi][kc*4];
        #pragma unroll
        for (int ni = 0; ni < 3; ++ni) bb[ni] = bp[ni][kc*4];
        #pragma unroll
        for (int mi = 0; mi < 3; ++mi)
            #pragma unroll
            for (int ni = 0; ni < 3; ++ni)
                acc[mi][ni] = __builtin_amdgcn_mfma_f32_16x16x32_bf16(a[mi], bb[ni], acc[mi][ni], 0,0,0);
        #pragma unroll
        for (int mi = 0; mi < 3; ++mi)
            #pragma unroll
            for (int j = 0; j < 8; ++j) {
                float va = us2f((unsigned short)a[mi][j]);
                float vb = us2f((unsigned short)bb[mi][j]);
                ssqa[mi] += va*va;
                ssqb[mi] += vb*vb;
            }
    }
    #pragma unroll
    for (int mi = 0; mi < 3; ++mi) {
        float va = ssqa[mi];
        va += __shfl_xor(va, 16); va += __shfl_xor(va, 32);
        float vb = ssqb[mi];
        vb += __shfl_xor(vb, 16); vb += __shfl_xor(vb, 32);
        if (lk == 0) { sqq[w][mi*16+lm] = va; sqk[w][mi*16+lm] = vb; }
    }
    #pragma unroll
    for (int mi = 0; mi < 3; ++mi)
        #pragma unroll
        for (int ni = 0; ni < 3; ++ni)
            #pragma unroll
            for (int r = 0; r < 4; ++r)
                ldsred[w][(mi*16 + lk*4 + r)*48 + ni*16 + lm] = acc[mi][ni][r];
    __syncthreads();
    float* dst = partial + ((size_t)bh*16 + ps)*2304;
    for (int idx = t; idx < 2304; idx += 256)
        dst[idx] = ldsred[0][idx] + ldsred[1][idx] + ldsred[2][idx] + ldsred[3][idx];
    if (t < 96) {
        float s = (t < 48) ? (sqq[0][t] + sqq[1][t] + sqq[2][t] + sqq[3][t])
                           : (sqk[0][t-48] + sqk[1][t-48] + sqk[2][t-48] + sqk[3][t-48]);
        ssqbuf[((size_t)bh*16 + ps)*96 + t] = s;
    }
}

// ---------------- attn partial reduction: 1 amat entry per thread --------------------
__global__ __launch_bounds__(256) void attn_reduce_kernel(const float* __restrict__ partial,
                                                          float* __restrict__ amat)
{
    int bh = blockIdx.x;
    int idx = blockIdx.y*256 + threadIdx.x;   // 9*256 = 2304
    const float* pb = partial + (size_t)bh*16*2304 + idx;
    float s = 0.f;
    #pragma unroll
    for (int ps = 0; ps < 16; ++ps) s += pb[ps*2304];
    amat[(size_t)bh*2304 + idx] = s;
}

// ---------------- finalize attention: all-LDS (no scratch arrays) --------------------
__global__ __launch_bounds__(256) void attn_finalize_kernel(const float* __restrict__ amat,
        const float* __restrict__ ssqbuf, const float* __restrict__ temp,
        const float* __restrict__ gparts, float* __restrict__ A)
{
    __shared__ float sa[2304];     // scaled logits
    __shared__ float em[2304];     // keep flag, then exp values
    __shared__ float qinv[48];
    __shared__ float kinv[48];
    __shared__ float dksh;
    int bh = blockIdx.x; int h = bh & 3;
    int t = threadIdx.x;
    if (t == 0) {
        float gs = 0.f;
        for (int k = 0; k < 512; ++k) gs += gparts[k];
        dksh = floorf(48.f * (gs / 65536.f));
    }
    if (t < 96) {
        float s = 0.f;
        for (int ps = 0; ps < 16; ++ps) s += ssqbuf[((size_t)bh*16 + ps)*96 + t];
        float inv = 1.f / fmaxf(sqrtf(s), 1e-12f);
        if (t < 48) qinv[t] = inv; else kinv[t-48] = inv;
    }
    __syncthreads();
    float tm = temp[h];
    const float* ab = amat + (size_t)bh*2304;
    for (int idx = t; idx < 2304; idx += 256) {
        int i = idx / 48, j = idx - i*48;
        sa[idx] = ab[idx] * qinv[i] * kinv[j] * tm;
    }
    __syncthreads();
    int dk = (int)dksh;
    if (dk > 48) dk = 48;
    for (int idx = t; idx < 2304; idx += 256) {
        int i = idx / 48, j = idx - i*48;
        float aj = sa[idx];
        const float* row = &sa[i*48];
        int r = 0;
        for (int l = 0; l < 48; ++l) {
            float al = row[l];
            r += (al > aj) || (al == aj && l < j);
        }
        em[idx] = (r < dk) ? 1.f : 0.f;
    }
    __syncthreads();
    if (t >= 48) return;
    int i = t;
    const float* row = &sa[i*48];
    float* erow = &em[i*48];
    float m = -1e30f;
    for (int j = 0; j < 48; ++j) if (erow[j] != 0.f) m = fmaxf(m, row[j]);
    float sum = 0.f;
    for (int j = 0; j < 48; ++j) {
        float e = (erow[j] != 0.f) ? expf(row[j] - m) : 0.f;
        erow[j] = e;
        sum += e;
    }
    float inv = 1.f / sum;
    float* dst = A + (size_t)bh*2304 + i*48;
    for (int j = 0; j < 48; ++j) dst[j] = erow[j]*inv;
}

// ---------------- PV: packed f32 pixel-pairs; writes out_attnT [b][p][192] -----------
// Thread: pixel pair (2*pp2, 2*pp2+1), 6 rows. Per-pixel f32 op order unchanged.
__global__ void attn_out_kernel(const float* __restrict__ A, const bf16* __restrict__ qkv,
                                bf16* __restrict__ out_attnT)
{
    int bh = blockIdx.x, ps = blockIdx.y;      // ps in 0..63 -> 256-px partition
    int b = bh >> 2, h = bh & 3;
    int t = threadIdx.x;
    __shared__ float As[48*48];
    __shared__ float vs[48][64];
    for (int idx = t; idx < 2304; idx += 256) As[idx] = A[(size_t)bh*2304 + idx];
    const bf16* vbase = qkv + ((size_t)b*C3 + 384 + h*48) * HWP;
    bf16* oT = out_attnT + (size_t)b*HWP*CCH;
    int pp2 = t & 31;                // pixel pair index (2 px each)
    int ig  = t >> 5;                // 8 groups x 6 rows
    for (int chunk = 0; chunk < 4; ++chunk) {
        int pc = ps*256 + chunk*64;
        __syncthreads();
        #pragma unroll
        for (int s = 0; s < 12; ++s) {
            int idx = t + s*256;
            int r = idx >> 6, c = idx & 63;
            vs[r][c] = b2f(vbase[(size_t)r*HWP + pc + c]);
        }
        __syncthreads();
        f32x2 acc2[6];
        #pragma unroll
        for (int ii = 0; ii < 6; ++ii) acc2[ii] = (f32x2){0.f, 0.f};
        for (int j = 0; j < 48; ++j) {
            f32x2 vv = *reinterpret_cast<const f32x2*>(&vs[j][pp2*2]);
            #pragma unroll
            for (int ii = 0; ii < 6; ++ii)
                acc2[ii] += vv * As[(ig*6+ii)*48 + j];
        }
        int p0a = pc + pp2*2;
        bf16* od0 = oT + (size_t)p0a*CCH + h*48 + ig*6;
        bf16* od1 = od0 + CCH;
        #pragma unroll
        for (int ii = 0; ii < 6; ++ii) {
            od0[ii] = f2b(acc2[ii].x);
            od1[ii] = f2b(acc2[ii].y);
        }
    }
}

extern "C" void kernel_launch(void* const* d_in, const int* in_sizes, int n_in,
                              void* d_out, int out_size, void* d_ws, size_t ws_size,
                              hipStream_t stream)
{
    const float* x        = (const float*)d_in[0];
    const float* temp     = (const float*)d_in[1];
    const float* qkv_w    = (const float*)d_in[2];
    const float* qkv_dw_w = (const float*)d_in[3];
    const float* proj_w   = (const float*)d_in[4];
    const float* fc_w     = (const float*)d_in[5];
    const float* fc_b     = (const float*)d_in[6];
    const float* dep_w    = (const float*)d_in[7];
    const float* dep_b    = (const float*)d_in[8];
    const float* gate_w1  = (const float*)d_in[9];
    const float* gate_b1  = (const float*)d_in[10];
    const float* gate_w2  = (const float*)d_in[11];
    const float* gate_b2  = (const float*)d_in[12];
    float* out = (float*)d_out;
    char* ws = (char*)d_ws;

    const size_t SZ_A = (size_t)BQ*C3*HWP*2;           // 75,497,472 B
    bf16* bufA   = (bf16*)(ws);                        // qkv (MFMA out), then f9s
    bf16* qkv_dw = (bf16*)(ws + SZ_A);
    bf16* slotC  = (bf16*)(ws + 2*SZ_A);               // xt, then out_attnT (25.2 MB)
    char* tail   = ws + 2*SZ_A + (size_t)BQ*HWP*CCH*2;
    float* attn_partial = (float*)tail;                // 16*16*2304 f32
    float* Abuf    = attn_partial + 16*16*2304;        // 16*2304
    float* amatbuf = Abuf + 16*2304;                   // 16*2304
    float* qkssq   = amatbuf + 16*2304;                // 16*16*96 f32
    float* gparts  = qkssq + 16*16*96;                 // 512 f32
    bf16*  qwt     = (bf16*)(gparts + 512);            // 576*192 bf16
    bf16*  pwt     = qwt + C3*CCH;                     // 192*192 bf16
    bf16*  w1t     = pwt + CCH*CCH;                    // 96*192 bf16
    bf16*  oconv   = w1t + GH*CCH;                     // BQ*192*HWP bf16 (25.2 MB)

    // 0. weight convert
    wcvt_kernel<<<dim3(432), 256, 0, stream>>>(qkv_w, qwt, proj_w, pwt, gate_w1, w1t);
    // 1. x -> xt bf16 [b][p][192]
    xcast_kernel<<<dim3(HWP/64, BQ), 256, 0, stream>>>(x, slotC);
    // 2. qkv + gate fused via MFMA (shared A registers) -> bufA + 512 gate partials
    mfma_qkv_gate_kernel<<<dim3(HWP/128, BQ), 256, 0, stream>>>(
        slotC, qwt, bufA, w1t, gate_b1, gate_w2, gate_b2, gparts);
    // 3. depthwise 3x3 (vectorized bf16 staging)
    dw3x3_kernel<<<dim3(16, C3, BQ), 256, 0, stream>>>(bufA, qkv_dw_w, qkv_dw);
    // 4. fc mixing (16 px/block, reuses bufA as f9s)
    fc9_kernel<<<dim3((BQ*HWP)/16), 256, 0, stream>>>(qkv_dw, fc_w, fc_b, bufA);
    // 5. grouped dep conv -> bf16 out_conv in ws
    depconv_kernel<<<dim3(16, 48, BQ), 256, 0, stream>>>(bufA, dep_w, dep_b, oconv);
    // 6. QK^T partials via MFMA + fused q/k sum-of-squares
    attn_dot_kernel<<<dim3(16,16), 256, 0, stream>>>(qkv_dw, attn_partial, qkssq);
    // 7a. parallel partial reduction -> amat (bit-identical ps order)
    attn_reduce_kernel<<<dim3(16,9), 256, 0, stream>>>(attn_partial, amatbuf);
    // 7b. finalize (all-LDS): norms, dynamic-k mask, softmax
    attn_finalize_kernel<<<dim3(16), 256, 0, stream>>>(amatbuf, qkssq, temp, gparts, Abuf);
    // 8. PV (packed f32 pixel-pairs) -> out_attnT [b][p][192]
    attn_out_kernel<<<dim3(16,64), 256, 0, stream>>>(Abuf, qkv_dw, slotC);
    // 9. proj via MFMA + add bf16 out_conv -> single f32 store to d_out
    mfma_projf_kernel<<<dim3(HWP/128, CCH/64, BQ), 256, 0, stream>>>(slotC, pwt, oconv, out);
}